// Round 4
// baseline (386.016 us; speedup 1.0000x reference)
//
#include <hip/hip_runtime.h>
#include <math.h>

#define L_ 8192
#define EMB_ 256
#define HID_ 64

// workspace layout (floats)
#define OFF_T    0           // float[64][8192]   synthesis rows (cos f / sin f)
#define OFF_TL   524288      // float[8192][64]   l-major analysis table
#define OFF_XFR  1048576     // float[2048][128]  parity DFT sums: [Ce(32) Se(32) Co(32) So(32)]
#define OFF_PHI  1310720     // float[32*32*4]
#define OFF_GB   1314816     // float2[32*64]     (1+gamma, beta)
#define OFF_AF   1318912     // float[32][128][64] mix output rows
#define OFF_APM  1581056     // float[32][192][64] rows 0..63 Ap, 64..127 Am, 128..191 Ax
#define OFF_B2   1974272     // float[32*64]

__global__ __launch_bounds__(256) void k_trig2(float* __restrict__ T, float* __restrict__ TL) {
    int idx = blockIdx.x * 256 + threadIdx.x;   // 0..1048575
    int f, l; bool sinp; float* dst;
    if (idx < 524288) {             // T[64][8192]: k<32 cos f=k; 32..63 sin
        int k = idx >> 13; l = idx & 8191;
        f = k & 31; sinp = (k & 32) != 0; dst = T + idx;
    } else {                        // TL[8192][64]: col<32 cos, 32..63 sin
        int j = idx - 524288;
        l = j >> 6; int kk = j & 63;
        f = kk & 31; sinp = (kk & 32) != 0; dst = TL + j;
    }
    int r = (f * l) & (L_ - 1);
    float ang = (float)r * (6.283185307179586f / (float)L_);
    *dst = sinp ? sinf(ang) : cosf(ang);
}

__global__ __launch_bounds__(256) void k_phi(const float* __restrict__ emb,
        const float* __restrict__ Arp, const float* __restrict__ Aip,
        const float* __restrict__ Arn, const float* __restrict__ Ain,
        float* __restrict__ phi) {
    int tid = blockIdx.x * 256 + threadIdx.x;   // (b*32+mm)*4+cmp
    int b = tid >> 7;
    int mm = (tid >> 2) & 31;
    int cmp = tid & 3;
    const float* A = (cmp == 0) ? Arp : (cmp == 1) ? Aip : (cmp == 2) ? Arn : Ain;
    const float4* e4 = (const float4*)(emb + b * EMB_);
    const float4* a4 = (const float4*)(A + mm * EMB_);
    float acc = 0.f;
    for (int q = 0; q < EMB_ / 4; ++q) {
        float4 ev = e4[q], av = a4[q];
        acc += ev.x * av.x + ev.y * av.y + ev.z * av.z + ev.w * av.w;
    }
    phi[tid] = acc;
}

__global__ __launch_bounds__(128) void k_mlp(const float* __restrict__ emb,
        const float* __restrict__ w1, const float* __restrict__ b1,
        const float* __restrict__ w2, const float* __restrict__ b2,
        float* __restrict__ gb) {
    __shared__ float h[HID_];
    int b = blockIdx.x, t = threadIdx.x;
    if (t < HID_) {
        const float4* e4 = (const float4*)(emb + b * EMB_);
        const float4* w4 = (const float4*)(w1 + t * EMB_);
        float acc = b1[t];
        for (int q = 0; q < EMB_ / 4; ++q) {
            float4 ev = e4[q], wv = w4[q];
            acc += ev.x * wv.x + ev.y * wv.y + ev.z * wv.z + ev.w * wv.w;
        }
        h[t] = acc / (1.f + expf(-acc));
    }
    __syncthreads();
    float g = b2[t];
    const float4* h4 = (const float4*)h;
    const float4* w4 = (const float4*)(w2 + t * HID_);
    for (int q = 0; q < HID_ / 4; ++q) {
        float4 hv = h4[q], wv = w4[q];
        g += hv.x * wv.x + hv.y * wv.y + hv.z * wv.z + hv.w * wv.w;
    }
    if (t < 64) gb[(b * 64 + t) * 2 + 0] = 1.f + g;
    else        gb[(b * 64 + (t - 64)) * 2 + 1] = g;
}

// parity-split DFT: XFR[row][p*64 + k'] = sum_{l==p (mod 2), l in seg} x[row][l] * TL[l][k']
// grid 512 = rowgrp(16 x 128 rows) * seg(32 x 256 l); threads 256 = kg(16: p*8+k8) x rg(16: 8 rows)
__global__ __launch_bounds__(256) void k_dft(const float* __restrict__ x,
        const float* __restrict__ TL, float* __restrict__ xfr) {
    __shared__ float sT[2][32][68];
    __shared__ float sX[2][32][132];
    int rowgrp = blockIdx.x >> 5;
    int seg = blockIdx.x & 31;
    int r0 = rowgrp * 128;
    int lbase = seg * 256;
    int tid = threadIdx.x;
    int kg = tid & 15, rg = tid >> 4;
    int p = kg >> 3, k8 = kg & 7;
    float acc[8][8];
    #pragma unroll
    for (int i = 0; i < 8; ++i)
        #pragma unroll
        for (int j = 0; j < 8; ++j) acc[i][j] = 0.f;

    float4 rT[2], rX[4];
    auto issue = [&](int c0) {
        const float4* tsrc = (const float4*)(TL + (size_t)(lbase + c0) * 64);
        rT[0] = tsrc[tid];
        rT[1] = tsrc[tid + 256];
        #pragma unroll
        for (int j = 0; j < 4; ++j) {
            int q = tid + 256 * j;
            int rr = q >> 3, c4 = q & 7;
            rX[j] = *(const float4*)(x + (size_t)(r0 + rr) * L_ + lbase + c0 + c4 * 4);
        }
    };
    auto lwrite = [&](int buf) {
        #pragma unroll
        for (int j = 0; j < 2; ++j) {
            int q = tid + 256 * j;
            int l = q >> 4, f4 = q & 15;
            *(float4*)&sT[buf][l][f4 * 4] = rT[j];
        }
        #pragma unroll
        for (int j = 0; j < 4; ++j) {
            int q = tid + 256 * j;
            int rr = q >> 3, c4 = q & 7;
            sX[buf][c4 * 4 + 0][rr] = rX[j].x;
            sX[buf][c4 * 4 + 1][rr] = rX[j].y;
            sX[buf][c4 * 4 + 2][rr] = rX[j].z;
            sX[buf][c4 * 4 + 3][rr] = rX[j].w;
        }
    };
    issue(0); lwrite(0); __syncthreads();
    for (int c = 0; c < 8; ++c) {
        if (c < 7) issue((c + 1) * 32);
        int buf = c & 1;
        #pragma unroll 2
        for (int lp = 0; lp < 16; ++lp) {
            int li = 2 * lp + p;
            float4 t0 = *(const float4*)&sT[buf][li][k8 * 8];
            float4 t1 = *(const float4*)&sT[buf][li][k8 * 8 + 4];
            float4 x0 = *(const float4*)&sX[buf][li][rg * 8];
            float4 x1 = *(const float4*)&sX[buf][li][rg * 8 + 4];
            float tv[8] = {t0.x,t0.y,t0.z,t0.w,t1.x,t1.y,t1.z,t1.w};
            float xv[8] = {x0.x,x0.y,x0.z,x0.w,x1.x,x1.y,x1.z,x1.w};
            #pragma unroll
            for (int rr = 0; rr < 8; ++rr)
                #pragma unroll
                for (int e = 0; e < 8; ++e)
                    acc[rr][e] += xv[rr] * tv[e];
        }
        if (c < 7) lwrite((c + 1) & 1);
        __syncthreads();
    }
    #pragma unroll
    for (int rr = 0; rr < 8; ++rr) {
        int row = r0 + rg * 8 + rr;
        #pragma unroll
        for (int e = 0; e < 8; ++e)
            atomicAdd(&xfr[(size_t)row * 128 + p * 64 + k8 * 8 + e], acc[rr][e]);
    }
}

// mode mixing -> AF rows 0..127 (per b)
__global__ __launch_bounds__(64) void k_mix(const float* __restrict__ xfr,
        const float* __restrict__ wpos, const float* __restrict__ wneg,
        const float* __restrict__ phi, float* __restrict__ afull) {
    __shared__ float xr[64], xi[64];
    int bi = blockIdx.x;
    int b = bi >> 6, rem = bi & 63, mm = rem >> 1, side = rem & 1;
    int o = threadIdx.x;
    int slot = side ? (31 - mm) : mm;
    const float* xb = xfr + (size_t)(b * 64 + o) * 128;
    if (!side) { xr[o] = xb[mm] + xb[64 + mm];     xi[o] = -(xb[32 + mm] + xb[96 + mm]); }
    else       { xr[o] = xb[slot] - xb[64 + slot]; xi[o] = xb[32 + slot] - xb[96 + slot]; }
    __syncthreads();
    const float* W = side ? wneg : wpos;
    float sre = 0.f, sim = 0.f;
    #pragma unroll 8
    for (int i = 0; i < 64; ++i) {
        float2 w = *(const float2*)&W[((size_t)(i * 64 + o) * 32 + mm) * 2];
        float xri = xr[i], xii = xi[i];
        sre += xri * w.x - xii * w.y;
        sim += xri * w.y + xii * w.x;
    }
    const float* ph = &phi[(b * 32 + mm) * 4 + (side ? 2 : 0)];
    float phr = ph[0], phim = ph[1];
    float Pre = sre * phr - sim * phim;
    float Pim = sre * phim + sim * phr;
    const float invL = 1.f / (float)L_;
    float fac = (slot == 0) ? invL : 2.f * invL;
    float a = fac * Pre;
    float bcoef = (slot == 0) ? 0.f : (side ? 2.f * invL * Pim : -2.f * invL * Pim);
    int comp = side ? 2 : 0;
    afull[((size_t)b * 128 + comp * 32 + slot) * 64 + o] = a;
    afull[((size_t)b * 128 + (comp + 1) * 32 + slot) * 64 + o] = bcoef;
}

// fold: Ap = A0+A1, Am = A0-A1, Ax = lw*(1+gamma); bias2 = lb*(1+gamma)+beta
__global__ __launch_bounds__(256) void k_folda(const float* __restrict__ lw,
        const float* __restrict__ lb, const float* __restrict__ gb,
        const float* __restrict__ af, float* __restrict__ apm, float* __restrict__ bias2) {
    int b = blockIdx.x, tid = threadIdx.x;
    const float* afb = af + (size_t)b * 128 * 64;
    float* ab = apm + (size_t)b * 192 * 64;
    #pragma unroll
    for (int j = 0; j < 16; ++j) {
        int e = tid + 256 * j;      // 0..4095
        int r = e >> 6, o = e & 63;
        float u = afb[r * 64 + o], v = afb[(64 + r) * 64 + o];
        ab[r * 64 + o] = u + v;
        ab[(64 + r) * 64 + o] = u - v;
        float g1 = gb[(b * 64 + o) * 2];
        ab[(128 + r) * 64 + o] = lw[o * 64 + r] * g1;
    }
    if (tid < 64) {
        float g1 = gb[(b * 64 + tid) * 2], be = gb[(b * 64 + tid) * 2 + 1];
        bias2[b * 64 + tid] = lb[tid] * g1 + be;
    }
}

// out[b,c,l] = silu( sum_{k<64} (l even ? Ap : Am)[k][c] * T[k][l] + sum_k Ax[k][c]*x[b,k,l] + bias2[c] )
__global__ __launch_bounds__(256) void k_fuse(const float* __restrict__ x,
        const float* __restrict__ T, const float* __restrict__ apm,
        const float* __restrict__ bias2, float* __restrict__ out) {
    __shared__ float sA[192][68];
    __shared__ float sB2[64];
    int b = blockIdx.x >> 5, tile = blockIdx.x & 31;
    int tid = threadIdx.x;
    int tc = tid >> 5, tl = tid & 31;
    {
        const float4* asrc = (const float4*)(apm + (size_t)b * 192 * 64);
        #pragma unroll
        for (int j = 0; j < 12; ++j) {
            int q = tid + 256 * j;
            int row = q >> 4, c4 = q & 15;
            *(float4*)&sA[row][c4 * 4] = asrc[q];
        }
        if (tid < 64) sB2[tid] = bias2[b * 64 + tid];
    }
    __syncthreads();
    int c0 = tc * 8;
    int lg = tile * 256 + tl * 8;
    float acc[8][8];
    #pragma unroll
    for (int i = 0; i < 8; ++i)
        #pragma unroll
        for (int j = 0; j < 8; ++j) acc[i][j] = 0.f;

    const float* Bp = T + lg;
    float4 cb0 = *(const float4*)(Bp);
    float4 cb1 = *(const float4*)(Bp + 4);
    #pragma unroll 4
    for (int k = 0; k < 64; ++k) {
        float4 nb0, nb1;
        if (k < 63) {
            nb0 = *(const float4*)(Bp + (size_t)(k + 1) * L_);
            nb1 = *(const float4*)(Bp + (size_t)(k + 1) * L_ + 4);
        }
        float4 p0 = *(const float4*)&sA[k][c0];
        float4 p1 = *(const float4*)&sA[k][c0 + 4];
        float4 m0 = *(const float4*)&sA[64 + k][c0];
        float4 m1 = *(const float4*)&sA[64 + k][c0 + 4];
        float ap[8] = {p0.x,p0.y,p0.z,p0.w,p1.x,p1.y,p1.z,p1.w};
        float am[8] = {m0.x,m0.y,m0.z,m0.w,m1.x,m1.y,m1.z,m1.w};
        float bv[8] = {cb0.x,cb0.y,cb0.z,cb0.w,cb1.x,cb1.y,cb1.z,cb1.w};
        #pragma unroll
        for (int ci = 0; ci < 8; ++ci) {
            acc[ci][0] += ap[ci] * bv[0]; acc[ci][1] += am[ci] * bv[1];
            acc[ci][2] += ap[ci] * bv[2]; acc[ci][3] += am[ci] * bv[3];
            acc[ci][4] += ap[ci] * bv[4]; acc[ci][5] += am[ci] * bv[5];
            acc[ci][6] += ap[ci] * bv[6]; acc[ci][7] += am[ci] * bv[7];
        }
        cb0 = nb0; cb1 = nb1;
    }
    const float* Xp = x + (size_t)b * 64 * L_ + lg;
    cb0 = *(const float4*)(Xp);
    cb1 = *(const float4*)(Xp + 4);
    #pragma unroll 4
    for (int k = 0; k < 64; ++k) {
        float4 nb0, nb1;
        if (k < 63) {
            nb0 = *(const float4*)(Xp + (size_t)(k + 1) * L_);
            nb1 = *(const float4*)(Xp + (size_t)(k + 1) * L_ + 4);
        }
        float4 a0 = *(const float4*)&sA[128 + k][c0];
        float4 a1 = *(const float4*)&sA[128 + k][c0 + 4];
        float av[8] = {a0.x,a0.y,a0.z,a0.w,a1.x,a1.y,a1.z,a1.w};
        float bv[8] = {cb0.x,cb0.y,cb0.z,cb0.w,cb1.x,cb1.y,cb1.z,cb1.w};
        #pragma unroll
        for (int ci = 0; ci < 8; ++ci)
            #pragma unroll
            for (int lj = 0; lj < 8; ++lj)
                acc[ci][lj] += av[ci] * bv[lj];
        cb0 = nb0; cb1 = nb1;
    }
    #pragma unroll
    for (int ci = 0; ci < 8; ++ci) {
        int c = c0 + ci;
        float bias = sB2[c];
        float vbuf[8];
        #pragma unroll
        for (int lj = 0; lj < 8; ++lj) {
            float v = acc[ci][lj] + bias;
            vbuf[lj] = v / (1.f + __expf(-v));
        }
        float* op = out + ((size_t)(b * 64 + c)) * L_ + lg;
        *(float4*)(op)     = *(float4*)&vbuf[0];
        *(float4*)(op + 4) = *(float4*)&vbuf[4];
    }
}

extern "C" void kernel_launch(void* const* d_in, const int* in_sizes, int n_in,
                              void* d_out, int out_size, void* d_ws, size_t ws_size,
                              hipStream_t stream) {
    const float* x    = (const float*)d_in[0];
    const float* emb  = (const float*)d_in[1];
    const float* wpos = (const float*)d_in[2];
    const float* wneg = (const float*)d_in[3];
    const float* Arp  = (const float*)d_in[4];
    const float* Aip  = (const float*)d_in[5];
    const float* Arn  = (const float*)d_in[6];
    const float* Ain  = (const float*)d_in[7];
    const float* w1   = (const float*)d_in[8];
    const float* b1   = (const float*)d_in[9];
    const float* w2   = (const float*)d_in[10];
    const float* b2   = (const float*)d_in[11];
    const float* lw   = (const float*)d_in[12];
    const float* lb   = (const float*)d_in[13];
    float* out = (float*)d_out;
    float* ws = (float*)d_ws;
    float* T    = ws + OFF_T;
    float* TL   = ws + OFF_TL;
    float* XFR  = ws + OFF_XFR;
    float* PHI  = ws + OFF_PHI;
    float* GB   = ws + OFF_GB;
    float* AF   = ws + OFF_AF;
    float* APM  = ws + OFF_APM;
    float* B2   = ws + OFF_B2;

    hipMemsetAsync(XFR, 0, 2048 * 128 * sizeof(float), stream);
    hipLaunchKernelGGL(k_trig2, dim3(4096), dim3(256), 0, stream, T, TL);
    hipLaunchKernelGGL(k_phi,   dim3(16),   dim3(256), 0, stream, emb, Arp, Aip, Arn, Ain, PHI);
    hipLaunchKernelGGL(k_mlp,   dim3(32),   dim3(128), 0, stream, emb, w1, b1, w2, b2, GB);
    hipLaunchKernelGGL(k_dft,   dim3(512),  dim3(256), 0, stream, x, TL, XFR);
    hipLaunchKernelGGL(k_mix,   dim3(2048), dim3(64),  0, stream, XFR, wpos, wneg, PHI, AF);
    hipLaunchKernelGGL(k_folda, dim3(32),   dim3(256), 0, stream, lw, lb, GB, AF, APM, B2);
    hipLaunchKernelGGL(k_fuse,  dim3(1024), dim3(256), 0, stream, x, T, APM, B2, out);
}

// Round 5
// 322.473 us; speedup vs baseline: 1.1970x; 1.1970x over previous
//
#include <hip/hip_runtime.h>
#include <math.h>

#define L_ 8192
#define EMB_ 256
#define HID_ 64

// workspace layout (floats)
#define OFF_T    0           // float[64][8192]   synthesis rows (cos f / sin f)
#define OFF_TL   524288      // float[2048][64][4] interleaved analysis table: TL4[l>>2][c][l&3]
#define OFF_XFR  1048576     // float[2048][128]  parity DFT sums: [Ce(32) Se(32) Co(32) So(32)]
#define OFF_PHI  1310720     // float[32*32*4]
#define OFF_GB   1314816     // float2[32*64]     (1+gamma, beta)
#define OFF_AF   1318912     // float[32][128][64] mix output rows
#define OFF_APM  1581056     // float[32][192][64] rows 0..63 Ap, 64..127 Am, 128..191 Ax
#define OFF_B2   1974272     // float[32*64]

__global__ __launch_bounds__(256) void k_trig2(float* __restrict__ T, float* __restrict__ TL) {
    int idx = blockIdx.x * 256 + threadIdx.x;   // 0..1048575
    int f, l; bool sinp; float* dst;
    if (idx < 524288) {             // T[64][8192]: k<32 cos f=k; 32..63 sin
        int k = idx >> 13; l = idx & 8191;
        f = k & 31; sinp = (k & 32) != 0; dst = T + idx;
    } else {                        // TL4[l>>2][kk][l&3]
        int j = idx - 524288;
        l = j >> 6; int kk = j & 63;
        f = kk & 31; sinp = (kk & 32) != 0;
        dst = TL + ((size_t)(l >> 2) * 256 + kk * 4 + (l & 3));
    }
    int r = (f * l) & (L_ - 1);
    float ang = (float)r * (6.283185307179586f / (float)L_);
    *dst = sinp ? sinf(ang) : cosf(ang);
}

__global__ __launch_bounds__(256) void k_phi(const float* __restrict__ emb,
        const float* __restrict__ Arp, const float* __restrict__ Aip,
        const float* __restrict__ Arn, const float* __restrict__ Ain,
        float* __restrict__ phi) {
    int tid = blockIdx.x * 256 + threadIdx.x;   // (b*32+mm)*4+cmp
    int b = tid >> 7;
    int mm = (tid >> 2) & 31;
    int cmp = tid & 3;
    const float* A = (cmp == 0) ? Arp : (cmp == 1) ? Aip : (cmp == 2) ? Arn : Ain;
    const float4* e4 = (const float4*)(emb + b * EMB_);
    const float4* a4 = (const float4*)(A + mm * EMB_);
    float acc = 0.f;
    for (int q = 0; q < EMB_ / 4; ++q) {
        float4 ev = e4[q], av = a4[q];
        acc += ev.x * av.x + ev.y * av.y + ev.z * av.z + ev.w * av.w;
    }
    phi[tid] = acc;
}

__global__ __launch_bounds__(128) void k_mlp(const float* __restrict__ emb,
        const float* __restrict__ w1, const float* __restrict__ b1,
        const float* __restrict__ w2, const float* __restrict__ b2,
        float* __restrict__ gb) {
    __shared__ float h[HID_];
    int b = blockIdx.x, t = threadIdx.x;
    if (t < HID_) {
        const float4* e4 = (const float4*)(emb + b * EMB_);
        const float4* w4 = (const float4*)(w1 + t * EMB_);
        float acc = b1[t];
        for (int q = 0; q < EMB_ / 4; ++q) {
            float4 ev = e4[q], wv = w4[q];
            acc += ev.x * wv.x + ev.y * wv.y + ev.z * wv.z + ev.w * wv.w;
        }
        h[t] = acc / (1.f + expf(-acc));
    }
    __syncthreads();
    float g = b2[t];
    const float4* h4 = (const float4*)h;
    const float4* w4 = (const float4*)(w2 + t * HID_);
    for (int q = 0; q < HID_ / 4; ++q) {
        float4 hv = h4[q], wv = w4[q];
        g += hv.x * wv.x + hv.y * wv.y + hv.z * wv.z + hv.w * wv.w;
    }
    if (t < 64) gb[(b * 64 + t) * 2 + 0] = 1.f + g;
    else        gb[(b * 64 + (t - 64)) * 2 + 1] = g;
}

// broadcast DFT: lane c owns cols (c, 64+c); wave: 16 rows x 512 l
// grid 512 = rowblock(32: 64 rows) x lseg(16: 512 l); 4 waves/block -> 16 rows/wave
__global__ __launch_bounds__(256) void k_dft(const float* __restrict__ x,
        const float* __restrict__ TL4, float* __restrict__ xfr) {
    int rowblock = blockIdx.x >> 4;
    int lseg = blockIdx.x & 15;
    int w = __builtin_amdgcn_readfirstlane((int)(threadIdx.x >> 6));
    int c = threadIdx.x & 63;
    int r0 = rowblock * 64 + w * 16;
    int lbase = lseg * 512;

    const float4* tl = (const float4*)(TL4 + (size_t)(lbase >> 2) * 256) + c;
    const float* xb = x + (size_t)r0 * L_ + lbase;

    float acc_e[16], acc_o[16];
    #pragma unroll
    for (int r = 0; r < 16; ++r) { acc_e[r] = 0.f; acc_o[r] = 0.f; }

    #pragma unroll 2
    for (int j = 0; j < 128; ++j) {
        float4 t4 = tl[(size_t)j * 64];
        #pragma unroll
        for (int r = 0; r < 16; ++r) {
            float4 xv = *(const float4*)(xb + (size_t)r * L_ + j * 4);
            acc_e[r] += xv.x * t4.x + xv.z * t4.z;
            acc_o[r] += xv.y * t4.y + xv.w * t4.w;
        }
    }
    #pragma unroll
    for (int r = 0; r < 16; ++r) {
        atomicAdd(&xfr[(size_t)(r0 + r) * 128 + c], acc_e[r]);
        atomicAdd(&xfr[(size_t)(r0 + r) * 128 + 64 + c], acc_o[r]);
    }
}

// mode mixing -> AF rows 0..127 (per b)
__global__ __launch_bounds__(64) void k_mix(const float* __restrict__ xfr,
        const float* __restrict__ wpos, const float* __restrict__ wneg,
        const float* __restrict__ phi, float* __restrict__ afull) {
    __shared__ float xr[64], xi[64];
    int bi = blockIdx.x;
    int b = bi >> 6, rem = bi & 63, mm = rem >> 1, side = rem & 1;
    int o = threadIdx.x;
    int slot = side ? (31 - mm) : mm;
    const float* xb = xfr + (size_t)(b * 64 + o) * 128;
    if (!side) { xr[o] = xb[mm] + xb[64 + mm];     xi[o] = -(xb[32 + mm] + xb[96 + mm]); }
    else       { xr[o] = xb[slot] - xb[64 + slot]; xi[o] = xb[32 + slot] - xb[96 + slot]; }
    __syncthreads();
    const float* W = side ? wneg : wpos;
    float sre = 0.f, sim = 0.f;
    #pragma unroll 8
    for (int i = 0; i < 64; ++i) {
        float2 w = *(const float2*)&W[((size_t)(i * 64 + o) * 32 + mm) * 2];
        float xri = xr[i], xii = xi[i];
        sre += xri * w.x - xii * w.y;
        sim += xri * w.y + xii * w.x;
    }
    const float* ph = &phi[(b * 32 + mm) * 4 + (side ? 2 : 0)];
    float phr = ph[0], phim = ph[1];
    float Pre = sre * phr - sim * phim;
    float Pim = sre * phim + sim * phr;
    const float invL = 1.f / (float)L_;
    float fac = (slot == 0) ? invL : 2.f * invL;
    float a = fac * Pre;
    float bcoef = (slot == 0) ? 0.f : (side ? 2.f * invL * Pim : -2.f * invL * Pim);
    int comp = side ? 2 : 0;
    afull[((size_t)b * 128 + comp * 32 + slot) * 64 + o] = a;
    afull[((size_t)b * 128 + (comp + 1) * 32 + slot) * 64 + o] = bcoef;
}

// fold: Ap = A0+A1, Am = A0-A1, Ax = lw*(1+gamma); bias2 = lb*(1+gamma)+beta
__global__ __launch_bounds__(256) void k_folda(const float* __restrict__ lw,
        const float* __restrict__ lb, const float* __restrict__ gb,
        const float* __restrict__ af, float* __restrict__ apm, float* __restrict__ bias2) {
    int b = blockIdx.x, tid = threadIdx.x;
    const float* afb = af + (size_t)b * 128 * 64;
    float* ab = apm + (size_t)b * 192 * 64;
    #pragma unroll
    for (int j = 0; j < 16; ++j) {
        int e = tid + 256 * j;      // 0..4095
        int r = e >> 6, o = e & 63;
        float u = afb[r * 64 + o], v = afb[(64 + r) * 64 + o];
        ab[r * 64 + o] = u + v;
        ab[(64 + r) * 64 + o] = u - v;
        float g1 = gb[(b * 64 + o) * 2];
        ab[(128 + r) * 64 + o] = lw[o * 64 + r] * g1;
    }
    if (tid < 64) {
        float g1 = gb[(b * 64 + tid) * 2], be = gb[(b * 64 + tid) * 2 + 1];
        bias2[b * 64 + tid] = lb[tid] * g1 + be;
    }
}

// out[b,c,l] = silu( sum_{k<64} (l even ? Ap : Am)[k][c] * T[k][l] + sum_k Ax[k][c]*x[b,k,l] + bias2[c] )
__global__ __launch_bounds__(256) void k_fuse(const float* __restrict__ x,
        const float* __restrict__ T, const float* __restrict__ apm,
        const float* __restrict__ bias2, float* __restrict__ out) {
    __shared__ float sA[192][68];
    __shared__ float sB2[64];
    int b = blockIdx.x >> 5, tile = blockIdx.x & 31;
    int tid = threadIdx.x;
    int tc = tid >> 5, tl = tid & 31;
    {
        const float4* asrc = (const float4*)(apm + (size_t)b * 192 * 64);
        #pragma unroll
        for (int j = 0; j < 12; ++j) {
            int q = tid + 256 * j;
            int row = q >> 4, c4 = q & 15;
            *(float4*)&sA[row][c4 * 4] = asrc[q];
        }
        if (tid < 64) sB2[tid] = bias2[b * 64 + tid];
    }
    __syncthreads();
    int c0 = tc * 8;
    int lg = tile * 256 + tl * 8;
    float acc[8][8];
    #pragma unroll
    for (int i = 0; i < 8; ++i)
        #pragma unroll
        for (int j = 0; j < 8; ++j) acc[i][j] = 0.f;

    const float* Bp = T + lg;
    float4 cb0 = *(const float4*)(Bp);
    float4 cb1 = *(const float4*)(Bp + 4);
    #pragma unroll 4
    for (int k = 0; k < 64; ++k) {
        float4 nb0, nb1;
        if (k < 63) {
            nb0 = *(const float4*)(Bp + (size_t)(k + 1) * L_);
            nb1 = *(const float4*)(Bp + (size_t)(k + 1) * L_ + 4);
        }
        float4 p0 = *(const float4*)&sA[k][c0];
        float4 p1 = *(const float4*)&sA[k][c0 + 4];
        float4 m0 = *(const float4*)&sA[64 + k][c0];
        float4 m1 = *(const float4*)&sA[64 + k][c0 + 4];
        float ap[8] = {p0.x,p0.y,p0.z,p0.w,p1.x,p1.y,p1.z,p1.w};
        float am[8] = {m0.x,m0.y,m0.z,m0.w,m1.x,m1.y,m1.z,m1.w};
        float bv[8] = {cb0.x,cb0.y,cb0.z,cb0.w,cb1.x,cb1.y,cb1.z,cb1.w};
        #pragma unroll
        for (int ci = 0; ci < 8; ++ci) {
            acc[ci][0] += ap[ci] * bv[0]; acc[ci][1] += am[ci] * bv[1];
            acc[ci][2] += ap[ci] * bv[2]; acc[ci][3] += am[ci] * bv[3];
            acc[ci][4] += ap[ci] * bv[4]; acc[ci][5] += am[ci] * bv[5];
            acc[ci][6] += ap[ci] * bv[6]; acc[ci][7] += am[ci] * bv[7];
        }
        cb0 = nb0; cb1 = nb1;
    }
    const float* Xp = x + (size_t)b * 64 * L_ + lg;
    cb0 = *(const float4*)(Xp);
    cb1 = *(const float4*)(Xp + 4);
    #pragma unroll 4
    for (int k = 0; k < 64; ++k) {
        float4 nb0, nb1;
        if (k < 63) {
            nb0 = *(const float4*)(Xp + (size_t)(k + 1) * L_);
            nb1 = *(const float4*)(Xp + (size_t)(k + 1) * L_ + 4);
        }
        float4 a0 = *(const float4*)&sA[128 + k][c0];
        float4 a1 = *(const float4*)&sA[128 + k][c0 + 4];
        float av[8] = {a0.x,a0.y,a0.z,a0.w,a1.x,a1.y,a1.z,a1.w};
        float bv[8] = {cb0.x,cb0.y,cb0.z,cb0.w,cb1.x,cb1.y,cb1.z,cb1.w};
        #pragma unroll
        for (int ci = 0; ci < 8; ++ci)
            #pragma unroll
            for (int lj = 0; lj < 8; ++lj)
                acc[ci][lj] += av[ci] * bv[lj];
        cb0 = nb0; cb1 = nb1;
    }
    #pragma unroll
    for (int ci = 0; ci < 8; ++ci) {
        int c = c0 + ci;
        float bias = sB2[c];
        float vbuf[8];
        #pragma unroll
        for (int lj = 0; lj < 8; ++lj) {
            float v = acc[ci][lj] + bias;
            vbuf[lj] = v / (1.f + __expf(-v));
        }
        float* op = out + ((size_t)(b * 64 + c)) * L_ + lg;
        *(float4*)(op)     = *(float4*)&vbuf[0];
        *(float4*)(op + 4) = *(float4*)&vbuf[4];
    }
}

extern "C" void kernel_launch(void* const* d_in, const int* in_sizes, int n_in,
                              void* d_out, int out_size, void* d_ws, size_t ws_size,
                              hipStream_t stream) {
    const float* x    = (const float*)d_in[0];
    const float* emb  = (const float*)d_in[1];
    const float* wpos = (const float*)d_in[2];
    const float* wneg = (const float*)d_in[3];
    const float* Arp  = (const float*)d_in[4];
    const float* Aip  = (const float*)d_in[5];
    const float* Arn  = (const float*)d_in[6];
    const float* Ain  = (const float*)d_in[7];
    const float* w1   = (const float*)d_in[8];
    const float* b1   = (const float*)d_in[9];
    const float* w2   = (const float*)d_in[10];
    const float* b2   = (const float*)d_in[11];
    const float* lw   = (const float*)d_in[12];
    const float* lb   = (const float*)d_in[13];
    float* out = (float*)d_out;
    float* ws = (float*)d_ws;
    float* T    = ws + OFF_T;
    float* TL   = ws + OFF_TL;
    float* XFR  = ws + OFF_XFR;
    float* PHI  = ws + OFF_PHI;
    float* GB   = ws + OFF_GB;
    float* AF   = ws + OFF_AF;
    float* APM  = ws + OFF_APM;
    float* B2   = ws + OFF_B2;

    hipMemsetAsync(XFR, 0, 2048 * 128 * sizeof(float), stream);
    hipLaunchKernelGGL(k_trig2, dim3(4096), dim3(256), 0, stream, T, TL);
    hipLaunchKernelGGL(k_phi,   dim3(16),   dim3(256), 0, stream, emb, Arp, Aip, Arn, Ain, PHI);
    hipLaunchKernelGGL(k_mlp,   dim3(32),   dim3(128), 0, stream, emb, w1, b1, w2, b2, GB);
    hipLaunchKernelGGL(k_dft,   dim3(512),  dim3(256), 0, stream, x, TL, XFR);
    hipLaunchKernelGGL(k_mix,   dim3(2048), dim3(64),  0, stream, XFR, wpos, wneg, PHI, AF);
    hipLaunchKernelGGL(k_folda, dim3(32),   dim3(256), 0, stream, lw, lb, GB, AF, APM, B2);
    hipLaunchKernelGGL(k_fuse,  dim3(1024), dim3(256), 0, stream, x, T, APM, B2, out);
}

// Round 6
// 278.743 us; speedup vs baseline: 1.3848x; 1.1569x over previous
//
#include <hip/hip_runtime.h>
#include <math.h>

#define L_ 8192
#define EMB_ 256
#define HID_ 64

// workspace layout (floats)
#define OFF_T    0           // float[64][8192]   synthesis rows (cos f / sin f)
#define OFF_TL   524288      // float[2048][64][4] interleaved analysis table: TL4[l>>2][c][l&3]
#define OFF_XFR  1048576     // float[2048][128]  parity DFT sums: [Ce(32) Se(32) Co(32) So(32)]
#define OFF_PHI  1310720     // float[32*32*4]
#define OFF_GB   1314816     // float2[32*64]     (1+gamma, beta)
#define OFF_AF   1318912     // float[32][128][64] mix output rows
#define OFF_APM  1581056     // float[32][192][64] rows 0..63 Ap, 64..127 Am, 128..191 Ax
#define OFF_B2   1974272     // float[32*64]

__global__ __launch_bounds__(256) void k_trig2(float* __restrict__ T, float* __restrict__ TL) {
    int idx = blockIdx.x * 256 + threadIdx.x;   // 0..1048575
    int f, l; bool sinp; float* dst;
    if (idx < 524288) {             // T[64][8192]: k<32 cos f=k; 32..63 sin
        int k = idx >> 13; l = idx & 8191;
        f = k & 31; sinp = (k & 32) != 0; dst = T + idx;
    } else {                        // TL4[l>>2][kk][l&3]
        int j = idx - 524288;
        l = j >> 6; int kk = j & 63;
        f = kk & 31; sinp = (kk & 32) != 0;
        dst = TL + ((size_t)(l >> 2) * 256 + kk * 4 + (l & 3));
    }
    int r = (f * l) & (L_ - 1);
    float ang = (float)r * (6.283185307179586f / (float)L_);
    *dst = sinp ? sinf(ang) : cosf(ang);
}

__global__ __launch_bounds__(256) void k_phi(const float* __restrict__ emb,
        const float* __restrict__ Arp, const float* __restrict__ Aip,
        const float* __restrict__ Arn, const float* __restrict__ Ain,
        float* __restrict__ phi) {
    int tid = blockIdx.x * 256 + threadIdx.x;   // (b*32+mm)*4+cmp
    int b = tid >> 7;
    int mm = (tid >> 2) & 31;
    int cmp = tid & 3;
    const float* A = (cmp == 0) ? Arp : (cmp == 1) ? Aip : (cmp == 2) ? Arn : Ain;
    const float4* e4 = (const float4*)(emb + b * EMB_);
    const float4* a4 = (const float4*)(A + mm * EMB_);
    float acc = 0.f;
    for (int q = 0; q < EMB_ / 4; ++q) {
        float4 ev = e4[q], av = a4[q];
        acc += ev.x * av.x + ev.y * av.y + ev.z * av.z + ev.w * av.w;
    }
    phi[tid] = acc;
}

__global__ __launch_bounds__(128) void k_mlp(const float* __restrict__ emb,
        const float* __restrict__ w1, const float* __restrict__ b1,
        const float* __restrict__ w2, const float* __restrict__ b2,
        float* __restrict__ gb) {
    __shared__ float h[HID_];
    int b = blockIdx.x, t = threadIdx.x;
    if (t < HID_) {
        const float4* e4 = (const float4*)(emb + b * EMB_);
        const float4* w4 = (const float4*)(w1 + t * EMB_);
        float acc = b1[t];
        for (int q = 0; q < EMB_ / 4; ++q) {
            float4 ev = e4[q], wv = w4[q];
            acc += ev.x * wv.x + ev.y * wv.y + ev.z * wv.z + ev.w * wv.w;
        }
        h[t] = acc / (1.f + expf(-acc));
    }
    __syncthreads();
    float g = b2[t];
    const float4* h4 = (const float4*)h;
    const float4* w4 = (const float4*)(w2 + t * HID_);
    for (int q = 0; q < HID_ / 4; ++q) {
        float4 hv = h4[q], wv = w4[q];
        g += hv.x * wv.x + hv.y * wv.y + hv.z * wv.z + hv.w * wv.w;
    }
    if (t < 64) gb[(b * 64 + t) * 2 + 0] = 1.f + g;
    else        gb[(b * 64 + (t - 64)) * 2 + 1] = g;
}

// broadcast DFT with explicit depth-1 register prefetch.
// lane c owns cols (c, 64+c); wave: 8 rows x 512 l
// grid 1024 = rowblock(64: 32 rows) x lseg(16: 512 l); 4 waves/block -> 8 rows/wave
__global__ __launch_bounds__(256, 4) void k_dft(const float* __restrict__ x,
        const float* __restrict__ TL4, float* __restrict__ xfr) {
    int rowblock = blockIdx.x >> 4;
    int lseg = blockIdx.x & 15;
    int w = threadIdx.x >> 6;
    int c = threadIdx.x & 63;
    int r0 = rowblock * 32 + w * 8;
    int lbase = lseg * 512;

    const float4* tl = (const float4*)(TL4 + (size_t)(lbase >> 2) * 256) + c;
    const float* xb = x + (size_t)r0 * L_ + lbase;

    float acc_e[8], acc_o[8];
    #pragma unroll
    for (int r = 0; r < 8; ++r) { acc_e[r] = 0.f; acc_o[r] = 0.f; }

    float4 tc = tl[0];
    float4 xc[8];
    #pragma unroll
    for (int r = 0; r < 8; ++r) xc[r] = *(const float4*)(xb + (size_t)r * L_);

    for (int j = 0; j < 128; ++j) {
        float4 tn;
        float4 xn[8];
        if (j < 127) {
            tn = tl[(size_t)(j + 1) * 64];
            #pragma unroll
            for (int r = 0; r < 8; ++r)
                xn[r] = *(const float4*)(xb + (size_t)r * L_ + (j + 1) * 4);
        }
        #pragma unroll
        for (int r = 0; r < 8; ++r) {
            acc_e[r] += xc[r].x * tc.x + xc[r].z * tc.z;
            acc_o[r] += xc[r].y * tc.y + xc[r].w * tc.w;
        }
        tc = tn;
        #pragma unroll
        for (int r = 0; r < 8; ++r) xc[r] = xn[r];
    }
    #pragma unroll
    for (int r = 0; r < 8; ++r) {
        atomicAdd(&xfr[(size_t)(r0 + r) * 128 + c], acc_e[r]);
        atomicAdd(&xfr[(size_t)(r0 + r) * 128 + 64 + c], acc_o[r]);
    }
}

// mode mixing -> AF rows 0..127 (per b)
__global__ __launch_bounds__(64) void k_mix(const float* __restrict__ xfr,
        const float* __restrict__ wpos, const float* __restrict__ wneg,
        const float* __restrict__ phi, float* __restrict__ afull) {
    __shared__ float xr[64], xi[64];
    int bi = blockIdx.x;
    int b = bi >> 6, rem = bi & 63, mm = rem >> 1, side = rem & 1;
    int o = threadIdx.x;
    int slot = side ? (31 - mm) : mm;
    const float* xb = xfr + (size_t)(b * 64 + o) * 128;
    if (!side) { xr[o] = xb[mm] + xb[64 + mm];     xi[o] = -(xb[32 + mm] + xb[96 + mm]); }
    else       { xr[o] = xb[slot] - xb[64 + slot]; xi[o] = xb[32 + slot] - xb[96 + slot]; }
    __syncthreads();
    const float* W = side ? wneg : wpos;
    float sre = 0.f, sim = 0.f;
    #pragma unroll 8
    for (int i = 0; i < 64; ++i) {
        float2 w = *(const float2*)&W[((size_t)(i * 64 + o) * 32 + mm) * 2];
        float xri = xr[i], xii = xi[i];
        sre += xri * w.x - xii * w.y;
        sim += xri * w.y + xii * w.x;
    }
    const float* ph = &phi[(b * 32 + mm) * 4 + (side ? 2 : 0)];
    float phr = ph[0], phim = ph[1];
    float Pre = sre * phr - sim * phim;
    float Pim = sre * phim + sim * phr;
    const float invL = 1.f / (float)L_;
    float fac = (slot == 0) ? invL : 2.f * invL;
    float a = fac * Pre;
    float bcoef = (slot == 0) ? 0.f : (side ? 2.f * invL * Pim : -2.f * invL * Pim);
    int comp = side ? 2 : 0;
    afull[((size_t)b * 128 + comp * 32 + slot) * 64 + o] = a;
    afull[((size_t)b * 128 + (comp + 1) * 32 + slot) * 64 + o] = bcoef;
}

// fold: Ap = A0+A1, Am = A0-A1, Ax = lw*(1+gamma); bias2 = lb*(1+gamma)+beta
__global__ __launch_bounds__(256) void k_folda(const float* __restrict__ lw,
        const float* __restrict__ lb, const float* __restrict__ gb,
        const float* __restrict__ af, float* __restrict__ apm, float* __restrict__ bias2) {
    int b = blockIdx.x, tid = threadIdx.x;
    const float* afb = af + (size_t)b * 128 * 64;
    float* ab = apm + (size_t)b * 192 * 64;
    #pragma unroll
    for (int j = 0; j < 16; ++j) {
        int e = tid + 256 * j;      // 0..4095
        int r = e >> 6, o = e & 63;
        float u = afb[r * 64 + o], v = afb[(64 + r) * 64 + o];
        ab[r * 64 + o] = u + v;
        ab[(64 + r) * 64 + o] = u - v;
        float g1 = gb[(b * 64 + o) * 2];
        ab[(128 + r) * 64 + o] = lw[o * 64 + r] * g1;
    }
    if (tid < 64) {
        float g1 = gb[(b * 64 + tid) * 2], be = gb[(b * 64 + tid) * 2 + 1];
        bias2[b * 64 + tid] = lb[tid] * g1 + be;
    }
}

// out[b,c,l] = silu( sum_{k<64} (l even ? Ap : Am)[k][c] * T[k][l] + sum_k Ax[k][c]*x[b,k,l] + bias2[c] )
__global__ __launch_bounds__(256) void k_fuse(const float* __restrict__ x,
        const float* __restrict__ T, const float* __restrict__ apm,
        const float* __restrict__ bias2, float* __restrict__ out) {
    __shared__ float sA[192][68];
    __shared__ float sB2[64];
    int b = blockIdx.x >> 5, tile = blockIdx.x & 31;
    int tid = threadIdx.x;
    int tc = tid >> 5, tl = tid & 31;
    {
        const float4* asrc = (const float4*)(apm + (size_t)b * 192 * 64);
        #pragma unroll
        for (int j = 0; j < 12; ++j) {
            int q = tid + 256 * j;
            int row = q >> 4, c4 = q & 15;
            *(float4*)&sA[row][c4 * 4] = asrc[q];
        }
        if (tid < 64) sB2[tid] = bias2[b * 64 + tid];
    }
    __syncthreads();
    int c0 = tc * 8;
    int lg = tile * 256 + tl * 8;
    float acc[8][8];
    #pragma unroll
    for (int i = 0; i < 8; ++i)
        #pragma unroll
        for (int j = 0; j < 8; ++j) acc[i][j] = 0.f;

    const float* Bp = T + lg;
    float4 cb0 = *(const float4*)(Bp);
    float4 cb1 = *(const float4*)(Bp + 4);
    #pragma unroll 4
    for (int k = 0; k < 64; ++k) {
        float4 nb0, nb1;
        if (k < 63) {
            nb0 = *(const float4*)(Bp + (size_t)(k + 1) * L_);
            nb1 = *(const float4*)(Bp + (size_t)(k + 1) * L_ + 4);
        }
        float4 p0 = *(const float4*)&sA[k][c0];
        float4 p1 = *(const float4*)&sA[k][c0 + 4];
        float4 m0 = *(const float4*)&sA[64 + k][c0];
        float4 m1 = *(const float4*)&sA[64 + k][c0 + 4];
        float ap[8] = {p0.x,p0.y,p0.z,p0.w,p1.x,p1.y,p1.z,p1.w};
        float am[8] = {m0.x,m0.y,m0.z,m0.w,m1.x,m1.y,m1.z,m1.w};
        float bv[8] = {cb0.x,cb0.y,cb0.z,cb0.w,cb1.x,cb1.y,cb1.z,cb1.w};
        #pragma unroll
        for (int ci = 0; ci < 8; ++ci) {
            acc[ci][0] += ap[ci] * bv[0]; acc[ci][1] += am[ci] * bv[1];
            acc[ci][2] += ap[ci] * bv[2]; acc[ci][3] += am[ci] * bv[3];
            acc[ci][4] += ap[ci] * bv[4]; acc[ci][5] += am[ci] * bv[5];
            acc[ci][6] += ap[ci] * bv[6]; acc[ci][7] += am[ci] * bv[7];
        }
        cb0 = nb0; cb1 = nb1;
    }
    const float* Xp = x + (size_t)b * 64 * L_ + lg;
    cb0 = *(const float4*)(Xp);
    cb1 = *(const float4*)(Xp + 4);
    #pragma unroll 4
    for (int k = 0; k < 64; ++k) {
        float4 nb0, nb1;
        if (k < 63) {
            nb0 = *(const float4*)(Xp + (size_t)(k + 1) * L_);
            nb1 = *(const float4*)(Xp + (size_t)(k + 1) * L_ + 4);
        }
        float4 a0 = *(const float4*)&sA[128 + k][c0];
        float4 a1 = *(const float4*)&sA[128 + k][c0 + 4];
        float av[8] = {a0.x,a0.y,a0.z,a0.w,a1.x,a1.y,a1.z,a1.w};
        float bv[8] = {cb0.x,cb0.y,cb0.z,cb0.w,cb1.x,cb1.y,cb1.z,cb1.w};
        #pragma unroll
        for (int ci = 0; ci < 8; ++ci)
            #pragma unroll
            for (int lj = 0; lj < 8; ++lj)
                acc[ci][lj] += av[ci] * bv[lj];
        cb0 = nb0; cb1 = nb1;
    }
    #pragma unroll
    for (int ci = 0; ci < 8; ++ci) {
        int c = c0 + ci;
        float bias = sB2[c];
        float vbuf[8];
        #pragma unroll
        for (int lj = 0; lj < 8; ++lj) {
            float v = acc[ci][lj] + bias;
            vbuf[lj] = v / (1.f + __expf(-v));
        }
        float* op = out + ((size_t)(b * 64 + c)) * L_ + lg;
        *(float4*)(op)     = *(float4*)&vbuf[0];
        *(float4*)(op + 4) = *(float4*)&vbuf[4];
    }
}

extern "C" void kernel_launch(void* const* d_in, const int* in_sizes, int n_in,
                              void* d_out, int out_size, void* d_ws, size_t ws_size,
                              hipStream_t stream) {
    const float* x    = (const float*)d_in[0];
    const float* emb  = (const float*)d_in[1];
    const float* wpos = (const float*)d_in[2];
    const float* wneg = (const float*)d_in[3];
    const float* Arp  = (const float*)d_in[4];
    const float* Aip  = (const float*)d_in[5];
    const float* Arn  = (const float*)d_in[6];
    const float* Ain  = (const float*)d_in[7];
    const float* w1   = (const float*)d_in[8];
    const float* b1   = (const float*)d_in[9];
    const float* w2   = (const float*)d_in[10];
    const float* b2   = (const float*)d_in[11];
    const float* lw   = (const float*)d_in[12];
    const float* lb   = (const float*)d_in[13];
    float* out = (float*)d_out;
    float* ws = (float*)d_ws;
    float* T    = ws + OFF_T;
    float* TL   = ws + OFF_TL;
    float* XFR  = ws + OFF_XFR;
    float* PHI  = ws + OFF_PHI;
    float* GB   = ws + OFF_GB;
    float* AF   = ws + OFF_AF;
    float* APM  = ws + OFF_APM;
    float* B2   = ws + OFF_B2;

    hipMemsetAsync(XFR, 0, 2048 * 128 * sizeof(float), stream);
    hipLaunchKernelGGL(k_trig2, dim3(4096), dim3(256), 0, stream, T, TL);
    hipLaunchKernelGGL(k_phi,   dim3(16),   dim3(256), 0, stream, emb, Arp, Aip, Arn, Ain, PHI);
    hipLaunchKernelGGL(k_mlp,   dim3(32),   dim3(128), 0, stream, emb, w1, b1, w2, b2, GB);
    hipLaunchKernelGGL(k_dft,   dim3(1024), dim3(256), 0, stream, x, TL, XFR);
    hipLaunchKernelGGL(k_mix,   dim3(2048), dim3(64),  0, stream, XFR, wpos, wneg, PHI, AF);
    hipLaunchKernelGGL(k_folda, dim3(32),   dim3(256), 0, stream, lw, lb, GB, AF, APM, B2);
    hipLaunchKernelGGL(k_fuse,  dim3(1024), dim3(256), 0, stream, x, T, APM, B2, out);
}

// Round 7
// 168.172 us; speedup vs baseline: 2.2954x; 1.6575x over previous
//
#include <hip/hip_runtime.h>
#include <math.h>

#define L_ 8192
#define EMB_ 256
#define HID_ 64

typedef __attribute__((ext_vector_type(8))) short bf16x8;
typedef __attribute__((ext_vector_type(4))) float f32x4;
typedef __attribute__((ext_vector_type(4))) int i32x4;

// workspace layout (floats)
#define OFF_T    0           // float[64][8192] synthesis rows (cos f / sin f)
#define OFF_TLB  524288      // ushort[256][4][64][16] bf16 hi/lo analysis frags (1M ushorts)
#define OFF_XFRP 1048576     // float[4][2048][128] per-Kseg DFT partial sums
#define OFF_AF   524288      // float[32][128][64]  (aliases TLB - dead after k_dft)
#define OFF_APM  1048576     // float[32][192][64]  (aliases XFRP - dead after k_mix)
#define OFF_B2   2097152     // float[32*64]
#define OFF_PHI  2099200     // float[32*32*4]
#define OFF_GB   2103296     // float2[32*64]

__device__ inline int pkbf(float a, float b) {
    int r;
    asm volatile("v_cvt_pk_bf16_f32 %0, %1, %2" : "=v"(r) : "v"(a), "v"(b));
    return r;
}
__device__ inline bf16x8 asbf(i32x4 v) { union { i32x4 i; bf16x8 h; } u; u.i = v; return u.h; }
#define MFMA(A,B,C) __builtin_amdgcn_mfma_f32_16x16x32_bf16((A),(B),(C),0,0,0)

__device__ inline ushort f2bf(float v) {
    unsigned b = __float_as_uint(v);
    return (ushort)((b + 0x7FFFu + ((b >> 16) & 1u)) >> 16);
}
__device__ inline float bf2f(ushort h) { return __uint_as_float(((unsigned)h) << 16); }

// T[64][8192]: k<32 cos(2pi k l/L); 32..63 sin.  TLB fragment table for cols 0..63.
__global__ __launch_bounds__(256) void k_trig2(float* __restrict__ T, ushort* __restrict__ TLB) {
    int idx = blockIdx.x * 256 + threadIdx.x;   // 0..1572863
    if (idx < 524288) {
        int k = idx >> 13; int l = idx & 8191;
        int f = k & 31; bool sinp = (k & 32) != 0;
        int r = (f * l) & (L_ - 1);
        float ang = (float)r * (6.283185307179586f / (float)L_);
        T[idx] = sinp ? sinf(ang) : cosf(ang);
    } else {
        int u = idx - 524288;            // [kstep 256][ct 4][lane 64][e 16]
        int e = u & 15;
        int lane = (u >> 4) & 63;
        int ct = (u >> 10) & 3;
        int kstep = u >> 12;
        int l = kstep * 32 + ((lane >> 4) << 3) + (e & 7);
        int col = ct * 16 + (lane & 15);
        int f = col & 31; bool sinp = (col & 32) != 0;
        int r = (f * l) & (L_ - 1);
        float ang = (float)r * (6.283185307179586f / (float)L_);
        float v = sinp ? sinf(ang) : cosf(ang);
        ushort hi = f2bf(v);
        TLB[u] = (e < 8) ? hi : f2bf(v - bf2f(hi));
    }
}

__global__ __launch_bounds__(256) void k_phi(const float* __restrict__ emb,
        const float* __restrict__ Arp, const float* __restrict__ Aip,
        const float* __restrict__ Arn, const float* __restrict__ Ain,
        float* __restrict__ phi) {
    int tid = blockIdx.x * 256 + threadIdx.x;   // (b*32+mm)*4+cmp
    int b = tid >> 7;
    int mm = (tid >> 2) & 31;
    int cmp = tid & 3;
    const float* A = (cmp == 0) ? Arp : (cmp == 1) ? Aip : (cmp == 2) ? Arn : Ain;
    const float4* e4 = (const float4*)(emb + b * EMB_);
    const float4* a4 = (const float4*)(A + mm * EMB_);
    float acc = 0.f;
    for (int q = 0; q < EMB_ / 4; ++q) {
        float4 ev = e4[q], av = a4[q];
        acc += ev.x * av.x + ev.y * av.y + ev.z * av.z + ev.w * av.w;
    }
    phi[tid] = acc;
}

__global__ __launch_bounds__(128) void k_mlp(const float* __restrict__ emb,
        const float* __restrict__ w1, const float* __restrict__ b1,
        const float* __restrict__ w2, const float* __restrict__ b2,
        float* __restrict__ gb) {
    __shared__ float h[HID_];
    int b = blockIdx.x, t = threadIdx.x;
    if (t < HID_) {
        const float4* e4 = (const float4*)(emb + b * EMB_);
        const float4* w4 = (const float4*)(w1 + t * EMB_);
        float acc = b1[t];
        for (int q = 0; q < EMB_ / 4; ++q) {
            float4 ev = e4[q], wv = w4[q];
            acc += ev.x * wv.x + ev.y * wv.y + ev.z * wv.z + ev.w * wv.w;
        }
        h[t] = acc / (1.f + expf(-acc));
    }
    __syncthreads();
    float g = b2[t];
    const float4* h4 = (const float4*)h;
    const float4* w4 = (const float4*)(w2 + t * HID_);
    for (int q = 0; q < HID_ / 4; ++q) {
        float4 hv = h4[q], wv = w4[q];
        g += hv.x * wv.x + hv.y * wv.y + hv.z * wv.z + hv.w * wv.w;
    }
    if (t < 64) gb[(b * 64 + t) * 2 + 0] = 1.f + g;
    else        gb[(b * 64 + (t - 64)) * 2 + 1] = g;
}

// split-bf16 MFMA DFT: XFRP[lseg][row][col] = sum over K-chunk of x[row][l]*trig_col(l)
// cols 0..63 from TLB; cols 64..127 = (-1)^l * cols 0..63 (in-frag sign flip of odd e)
// grid 512 = stripe(128: 16 rows) x lseg(4: K=2048); 4 waves split K (512 each)
__global__ __launch_bounds__(256) void k_dft(const float* __restrict__ x,
        const ushort* __restrict__ TLB, float* __restrict__ xfrp) {
    __shared__ float sP[4][16][132];
    int stripe = blockIdx.x >> 2;
    int lseg = blockIdx.x & 3;
    int w = threadIdx.x >> 6;
    int lane = threadIdx.x & 63;
    int row = lane & 15, koff = (lane >> 4) << 3;
    int r0 = stripe * 16;
    int kb0 = lseg * 2048 + w * 512;

    f32x4 acc[8];
    #pragma unroll
    for (int i = 0; i < 8; ++i) acc[i] = (f32x4){0.f, 0.f, 0.f, 0.f};

    const float* ap = x + (size_t)(r0 + row) * L_ + kb0 + koff;
    const i32x4* tb = (const i32x4*)TLB;
    int tbase = (((kb0 >> 5) * 4) * 64 + lane) * 2;      // +512 per kstep
    const i32x4 SM = {(int)0x80000000, (int)0x80000000, (int)0x80000000, (int)0x80000000};

    for (int ks = 0; ks < 16; ++ks) {
        float4 xa = *(const float4*)(ap + ks * 32);
        float4 xc = *(const float4*)(ap + ks * 32 + 4);
        int h0 = pkbf(xa.x, xa.y), h1 = pkbf(xa.z, xa.w);
        int h2 = pkbf(xc.x, xc.y), h3 = pkbf(xc.z, xc.w);
        float e0 = xa.x - __uint_as_float(((unsigned)h0) << 16);
        float e1 = xa.y - __uint_as_float(((unsigned)h0) & 0xFFFF0000u);
        float e2 = xa.z - __uint_as_float(((unsigned)h1) << 16);
        float e3 = xa.w - __uint_as_float(((unsigned)h1) & 0xFFFF0000u);
        float e4 = xc.x - __uint_as_float(((unsigned)h2) << 16);
        float e5 = xc.y - __uint_as_float(((unsigned)h2) & 0xFFFF0000u);
        float e6 = xc.z - __uint_as_float(((unsigned)h3) << 16);
        float e7 = xc.w - __uint_as_float(((unsigned)h3) & 0xFFFF0000u);
        i32x4 ahi = {h0, h1, h2, h3};
        i32x4 alo = {pkbf(e0, e1), pkbf(e2, e3), pkbf(e4, e5), pkbf(e6, e7)};
        bf16x8 AH = asbf(ahi), AL = asbf(alo);
        int tix = tbase + ks * 512;
        #pragma unroll
        for (int ct = 0; ct < 4; ++ct) {
            i32x4 bh = tb[tix + ct * 128];
            i32x4 bl = tb[tix + ct * 128 + 1];
            bf16x8 BH = asbf(bh), BL = asbf(bl);
            acc[ct] = MFMA(AH, BH, acc[ct]);
            acc[ct] = MFMA(AL, BH, acc[ct]);
            acc[ct] = MFMA(AH, BL, acc[ct]);
            bf16x8 BH2 = asbf(bh ^ SM), BL2 = asbf(bl ^ SM);
            acc[ct + 4] = MFMA(AH, BH2, acc[ct + 4]);
            acc[ct + 4] = MFMA(AL, BH2, acc[ct + 4]);
            acc[ct + 4] = MFMA(AH, BL2, acc[ct + 4]);
        }
    }
    int crow = (lane >> 4) << 2;
    int ccol = lane & 15;
    #pragma unroll
    for (int ct = 0; ct < 8; ++ct)
        #pragma unroll
        for (int r = 0; r < 4; ++r)
            sP[w][crow + r][ct * 16 + ccol] = acc[ct][r];
    __syncthreads();
    #pragma unroll
    for (int i = 0; i < 8; ++i) {
        int e = threadIdx.x + 256 * i;     // 0..2047
        int rr = e >> 7, cc = e & 127;
        float s = sP[0][rr][cc] + sP[1][rr][cc] + sP[2][rr][cc] + sP[3][rr][cc];
        xfrp[((size_t)(lseg * 2048 + r0 + rr)) * 128 + cc] = s;
    }
}

// mode mixing -> AF rows 0..127 (per b). Direct-frequency cols:
// C_f = col[f], S_f = col[32+f], Cn_f = col[64+f], Sn_f = col[96+f] (freq 4096+f)
__global__ __launch_bounds__(64) void k_mix(const float* __restrict__ xfrp,
        const float* __restrict__ wpos, const float* __restrict__ wneg,
        const float* __restrict__ phi, float* __restrict__ afull) {
    __shared__ float xr[64], xi[64];
    int bi = blockIdx.x;
    int b = bi >> 6, rem = bi & 63, mm = rem >> 1, side = rem & 1;
    int o = threadIdx.x;
    int slot = side ? (31 - mm) : mm;
    size_t base = (size_t)(b * 64 + o) * 128;
    float vr = 0.f, vi = 0.f;
    if (!side) {
        #pragma unroll
        for (int s = 0; s < 4; ++s) {
            vr += xfrp[(size_t)s * 262144 + base + mm];
            vi += xfrp[(size_t)s * 262144 + base + 32 + mm];
        }
        xr[o] = vr; xi[o] = -vi;
    } else {
        #pragma unroll
        for (int s = 0; s < 4; ++s) {
            vr += xfrp[(size_t)s * 262144 + base + 64 + slot];
            vi += xfrp[(size_t)s * 262144 + base + 96 + slot];
        }
        xr[o] = vr; xi[o] = vi;
    }
    __syncthreads();
    const float* W = side ? wneg : wpos;
    float sre = 0.f, sim = 0.f;
    #pragma unroll 8
    for (int i = 0; i < 64; ++i) {
        float2 w = *(const float2*)&W[((size_t)(i * 64 + o) * 32 + mm) * 2];
        float xri = xr[i], xii = xi[i];
        sre += xri * w.x - xii * w.y;
        sim += xri * w.y + xii * w.x;
    }
    const float* ph = &phi[(b * 32 + mm) * 4 + (side ? 2 : 0)];
    float phr = ph[0], phim = ph[1];
    float Pre = sre * phr - sim * phim;
    float Pim = sre * phim + sim * phr;
    const float invL = 1.f / (float)L_;
    float fac = (slot == 0) ? invL : 2.f * invL;
    float a = fac * Pre;
    float bcoef = (slot == 0) ? 0.f : (side ? 2.f * invL * Pim : -2.f * invL * Pim);
    int comp = side ? 2 : 0;
    afull[((size_t)b * 128 + comp * 32 + slot) * 64 + o] = a;
    afull[((size_t)b * 128 + (comp + 1) * 32 + slot) * 64 + o] = bcoef;
}

// fold: Ap = A0+A1, Am = A0-A1, Ax = lw*(1+gamma); bias2 = lb*(1+gamma)+beta
__global__ __launch_bounds__(256) void k_folda(const float* __restrict__ lw,
        const float* __restrict__ lb, const float* __restrict__ gb,
        const float* __restrict__ af, float* __restrict__ apm, float* __restrict__ bias2) {
    int b = blockIdx.x, tid = threadIdx.x;
    const float* afb = af + (size_t)b * 128 * 64;
    float* ab = apm + (size_t)b * 192 * 64;
    #pragma unroll
    for (int j = 0; j < 16; ++j) {
        int e = tid + 256 * j;      // 0..4095
        int r = e >> 6, o = e & 63;
        float u = afb[r * 64 + o], v = afb[(64 + r) * 64 + o];
        ab[r * 64 + o] = u + v;
        ab[(64 + r) * 64 + o] = u - v;
        float g1 = gb[(b * 64 + o) * 2];
        ab[(128 + r) * 64 + o] = lw[o * 64 + r] * g1;
    }
    if (tid < 64) {
        float g1 = gb[(b * 64 + tid) * 2], be = gb[(b * 64 + tid) * 2 + 1];
        bias2[b * 64 + tid] = lb[tid] * g1 + be;
    }
}

// out[b,c,l] = silu( sum_{k<64} (l even ? Ap : Am)[k][c]*T[k][l] + sum_k Ax[k][c]*x[b,k,l] + bias2[c] )
__global__ __launch_bounds__(256) void k_fuse(const float* __restrict__ x,
        const float* __restrict__ T, const float* __restrict__ apm,
        const float* __restrict__ bias2, float* __restrict__ out) {
    __shared__ float sA[192][68];
    __shared__ float sB2[64];
    int b = blockIdx.x >> 5, tile = blockIdx.x & 31;
    int tid = threadIdx.x;
    int tc = tid >> 5, tl = tid & 31;
    {
        const float4* asrc = (const float4*)(apm + (size_t)b * 192 * 64);
        #pragma unroll
        for (int j = 0; j < 12; ++j) {
            int q = tid + 256 * j;
            int row = q >> 4, c4 = q & 15;
            *(float4*)&sA[row][c4 * 4] = asrc[q];
        }
        if (tid < 64) sB2[tid] = bias2[b * 64 + tid];
    }
    __syncthreads();
    int c0 = tc * 8;
    int lg = tile * 256 + tl * 8;
    float acc[8][8];
    #pragma unroll
    for (int i = 0; i < 8; ++i)
        #pragma unroll
        for (int j = 0; j < 8; ++j) acc[i][j] = 0.f;

    const float* Bp = T + lg;
    float4 cb0 = *(const float4*)(Bp);
    float4 cb1 = *(const float4*)(Bp + 4);
    #pragma unroll 4
    for (int k = 0; k < 64; ++k) {
        float4 nb0, nb1;
        if (k < 63) {
            nb0 = *(const float4*)(Bp + (size_t)(k + 1) * L_);
            nb1 = *(const float4*)(Bp + (size_t)(k + 1) * L_ + 4);
        }
        float4 p0 = *(const float4*)&sA[k][c0];
        float4 p1 = *(const float4*)&sA[k][c0 + 4];
        float4 m0 = *(const float4*)&sA[64 + k][c0];
        float4 m1 = *(const float4*)&sA[64 + k][c0 + 4];
        float ap[8] = {p0.x,p0.y,p0.z,p0.w,p1.x,p1.y,p1.z,p1.w};
        float am[8] = {m0.x,m0.y,m0.z,m0.w,m1.x,m1.y,m1.z,m1.w};
        float bv[8] = {cb0.x,cb0.y,cb0.z,cb0.w,cb1.x,cb1.y,cb1.z,cb1.w};
        #pragma unroll
        for (int ci = 0; ci < 8; ++ci) {
            acc[ci][0] += ap[ci] * bv[0]; acc[ci][1] += am[ci] * bv[1];
            acc[ci][2] += ap[ci] * bv[2]; acc[ci][3] += am[ci] * bv[3];
            acc[ci][4] += ap[ci] * bv[4]; acc[ci][5] += am[ci] * bv[5];
            acc[ci][6] += ap[ci] * bv[6]; acc[ci][7] += am[ci] * bv[7];
        }
        cb0 = nb0; cb1 = nb1;
    }
    const float* Xp = x + (size_t)b * 64 * L_ + lg;
    cb0 = *(const float4*)(Xp);
    cb1 = *(const float4*)(Xp + 4);
    #pragma unroll 4
    for (int k = 0; k < 64; ++k) {
        float4 nb0, nb1;
        if (k < 63) {
            nb0 = *(const float4*)(Xp + (size_t)(k + 1) * L_);
            nb1 = *(const float4*)(Xp + (size_t)(k + 1) * L_ + 4);
        }
        float4 a0 = *(const float4*)&sA[128 + k][c0];
        float4 a1 = *(const float4*)&sA[128 + k][c0 + 4];
        float av[8] = {a0.x,a0.y,a0.z,a0.w,a1.x,a1.y,a1.z,a1.w};
        float bv[8] = {cb0.x,cb0.y,cb0.z,cb0.w,cb1.x,cb1.y,cb1.z,cb1.w};
        #pragma unroll
        for (int ci = 0; ci < 8; ++ci)
            #pragma unroll
            for (int lj = 0; lj < 8; ++lj)
                acc[ci][lj] += av[ci] * bv[lj];
        cb0 = nb0; cb1 = nb1;
    }
    #pragma unroll
    for (int ci = 0; ci < 8; ++ci) {
        int c = c0 + ci;
        float bias = sB2[c];
        float vbuf[8];
        #pragma unroll
        for (int lj = 0; lj < 8; ++lj) {
            float v = acc[ci][lj] + bias;
            vbuf[lj] = v / (1.f + __expf(-v));
        }
        float* op = out + ((size_t)(b * 64 + c)) * L_ + lg;
        *(float4*)(op)     = *(float4*)&vbuf[0];
        *(float4*)(op + 4) = *(float4*)&vbuf[4];
    }
}

extern "C" void kernel_launch(void* const* d_in, const int* in_sizes, int n_in,
                              void* d_out, int out_size, void* d_ws, size_t ws_size,
                              hipStream_t stream) {
    const float* x    = (const float*)d_in[0];
    const float* emb  = (const float*)d_in[1];
    const float* wpos = (const float*)d_in[2];
    const float* wneg = (const float*)d_in[3];
    const float* Arp  = (const float*)d_in[4];
    const float* Aip  = (const float*)d_in[5];
    const float* Arn  = (const float*)d_in[6];
    const float* Ain  = (const float*)d_in[7];
    const float* w1   = (const float*)d_in[8];
    const float* b1   = (const float*)d_in[9];
    const float* w2   = (const float*)d_in[10];
    const float* b2   = (const float*)d_in[11];
    const float* lw   = (const float*)d_in[12];
    const float* lb   = (const float*)d_in[13];
    float* out = (float*)d_out;
    float* ws = (float*)d_ws;
    float*  T    = ws + OFF_T;
    ushort* TLB  = (ushort*)(ws + OFF_TLB);
    float*  XFRP = ws + OFF_XFRP;
    float*  AF   = ws + OFF_AF;
    float*  APM  = ws + OFF_APM;
    float*  B2   = ws + OFF_B2;
    float*  PHI  = ws + OFF_PHI;
    float*  GB   = ws + OFF_GB;

    hipLaunchKernelGGL(k_trig2, dim3(6144), dim3(256), 0, stream, T, TLB);
    hipLaunchKernelGGL(k_phi,   dim3(16),   dim3(256), 0, stream, emb, Arp, Aip, Arn, Ain, PHI);
    hipLaunchKernelGGL(k_mlp,   dim3(32),   dim3(128), 0, stream, emb, w1, b1, w2, b2, GB);
    hipLaunchKernelGGL(k_dft,   dim3(512),  dim3(256), 0, stream, x, TLB, XFRP);
    hipLaunchKernelGGL(k_mix,   dim3(2048), dim3(64),  0, stream, XFRP, wpos, wneg, PHI, AF);
    hipLaunchKernelGGL(k_folda, dim3(32),   dim3(256), 0, stream, lw, lb, GB, AF, APM, B2);
    hipLaunchKernelGGL(k_fuse,  dim3(1024), dim3(256), 0, stream, x, T, APM, B2, out);
}

// Round 8
// 131.918 us; speedup vs baseline: 2.9262x; 1.2748x over previous
//
#include <hip/hip_runtime.h>
#include <math.h>

#define L_ 8192
#define EMB_ 256
#define HID_ 64

typedef __attribute__((ext_vector_type(8))) short bf16x8;
typedef __attribute__((ext_vector_type(4))) float f32x4;
typedef __attribute__((ext_vector_type(4))) int i32x4;

// workspace layout (floats)
#define OFF_TFB  0           // ushort[512][2][64][16] synthesis B-frag table (2 MB)
#define OFF_TLB  524288      // ushort[256][4][64][16] analysis B-frag table (dead after k_dft)
#define OFF_AFB  524288      // ushort[32][6][4][64][16] A-frag table (aliases TLB; written by k_folda)
#define OFF_XFRP 1048576     // float[4][2048][128] per-Kseg DFT partial sums
#define OFF_AF   2097152     // float[32][128][64]  mix output rows
#define OFF_B2   2359296     // float[32*64]
#define OFF_PHI  2361344     // float[32*32*4]
#define OFF_GB   2365440     // float2[32*64]

__device__ inline int pkbf(float a, float b) {
    int r;
    asm volatile("v_cvt_pk_bf16_f32 %0, %1, %2" : "=v"(r) : "v"(a), "v"(b));
    return r;
}
__device__ inline bf16x8 asbf(i32x4 v) { union { i32x4 i; bf16x8 h; } u; u.i = v; return u.h; }
#define MFMA(A,B,C) __builtin_amdgcn_mfma_f32_16x16x32_bf16((A),(B),(C),0,0,0)

__device__ inline ushort f2bf(float v) {
    unsigned b = __float_as_uint(v);
    return (ushort)((b + 0x7FFFu + ((b >> 16) & 1u)) >> 16);
}
__device__ inline float bf2f(ushort h) { return __uint_as_float(((unsigned)h) << 16); }
__device__ inline float lo16f(int h) { return __uint_as_float(((unsigned)h) << 16); }
__device__ inline float hi16f(int h) { return __uint_as_float(((unsigned)h) & 0xFFFF0000u); }

// TLB: analysis frags [kstep 256][ct 4][lane 64][e16]; TFB: synthesis frags [ltile 512][ts 2][lane 64][e16]
__global__ __launch_bounds__(256) void k_trig2(ushort* __restrict__ TLB, ushort* __restrict__ TFB) {
    int idx = blockIdx.x * 256 + threadIdx.x;   // 0..2097151
    int f, l; ushort* dst; bool lohalf;
    if (idx < 1048576) {
        int u = idx;
        int e = u & 15, lane = (u >> 4) & 63, ct = (u >> 10) & 3, kstep = u >> 12;
        l = kstep * 32 + ((lane >> 4) << 3) + (e & 7);
        int colf = ct * 16 + (lane & 15);
        f = colf;                                // 0..31 cos, 32..63 sin
        dst = TLB + u; lohalf = (e >= 8);
    } else {
        int u = idx - 1048576;
        int e = u & 15, lane = (u >> 4) & 63, ts = (u >> 10) & 1, lt = u >> 11;
        l = lt * 16 + (lane & 15);
        f = ts * 32 + ((lane >> 4) << 3) + (e & 7);
        dst = TFB + u; lohalf = (e >= 8);
    }
    int fr = f & 31; bool sinp = (f & 32) != 0;
    int r = (fr * l) & (L_ - 1);
    float ang = (float)r * (6.283185307179586f / (float)L_);
    float v = sinp ? sinf(ang) : cosf(ang);
    ushort hi = f2bf(v);
    *dst = lohalf ? f2bf(v - bf2f(hi)) : hi;
}

__global__ __launch_bounds__(256) void k_phi(const float* __restrict__ emb,
        const float* __restrict__ Arp, const float* __restrict__ Aip,
        const float* __restrict__ Arn, const float* __restrict__ Ain,
        float* __restrict__ phi) {
    int tid = blockIdx.x * 256 + threadIdx.x;   // (b*32+mm)*4+cmp
    int b = tid >> 7;
    int mm = (tid >> 2) & 31;
    int cmp = tid & 3;
    const float* A = (cmp == 0) ? Arp : (cmp == 1) ? Aip : (cmp == 2) ? Arn : Ain;
    const float4* e4 = (const float4*)(emb + b * EMB_);
    const float4* a4 = (const float4*)(A + mm * EMB_);
    float acc = 0.f;
    for (int q = 0; q < EMB_ / 4; ++q) {
        float4 ev = e4[q], av = a4[q];
        acc += ev.x * av.x + ev.y * av.y + ev.z * av.z + ev.w * av.w;
    }
    phi[tid] = acc;
}

__global__ __launch_bounds__(128) void k_mlp(const float* __restrict__ emb,
        const float* __restrict__ w1, const float* __restrict__ b1,
        const float* __restrict__ w2, const float* __restrict__ b2,
        float* __restrict__ gb) {
    __shared__ float h[HID_];
    int b = blockIdx.x, t = threadIdx.x;
    if (t < HID_) {
        const float4* e4 = (const float4*)(emb + b * EMB_);
        const float4* w4 = (const float4*)(w1 + t * EMB_);
        float acc = b1[t];
        for (int q = 0; q < EMB_ / 4; ++q) {
            float4 ev = e4[q], wv = w4[q];
            acc += ev.x * wv.x + ev.y * wv.y + ev.z * wv.z + ev.w * wv.w;
        }
        h[t] = acc / (1.f + expf(-acc));
    }
    __syncthreads();
    float g = b2[t];
    const float4* h4 = (const float4*)h;
    const float4* w4 = (const float4*)(w2 + t * HID_);
    for (int q = 0; q < HID_ / 4; ++q) {
        float4 hv = h4[q], wv = w4[q];
        g += hv.x * wv.x + hv.y * wv.y + hv.z * wv.z + hv.w * wv.w;
    }
    if (t < 64) gb[(b * 64 + t) * 2 + 0] = 1.f + g;
    else        gb[(b * 64 + (t - 64)) * 2 + 1] = g;
}

// split-bf16 MFMA DFT (unchanged from round 6, TLB relocated)
__global__ __launch_bounds__(256) void k_dft(const float* __restrict__ x,
        const ushort* __restrict__ TLB, float* __restrict__ xfrp) {
    __shared__ float sP[4][16][132];
    int stripe = blockIdx.x >> 2;
    int lseg = blockIdx.x & 3;
    int w = threadIdx.x >> 6;
    int lane = threadIdx.x & 63;
    int row = lane & 15, koff = (lane >> 4) << 3;
    int r0 = stripe * 16;
    int kb0 = lseg * 2048 + w * 512;

    f32x4 acc[8];
    #pragma unroll
    for (int i = 0; i < 8; ++i) acc[i] = (f32x4){0.f, 0.f, 0.f, 0.f};

    const float* ap = x + (size_t)(r0 + row) * L_ + kb0 + koff;
    const i32x4* tb = (const i32x4*)TLB;
    int tbase = (((kb0 >> 5) * 4) * 64 + lane) * 2;      // +512 per kstep
    const i32x4 SM = {(int)0x80000000, (int)0x80000000, (int)0x80000000, (int)0x80000000};

    for (int ks = 0; ks < 16; ++ks) {
        float4 xa = *(const float4*)(ap + ks * 32);
        float4 xc = *(const float4*)(ap + ks * 32 + 4);
        int h0 = pkbf(xa.x, xa.y), h1 = pkbf(xa.z, xa.w);
        int h2 = pkbf(xc.x, xc.y), h3 = pkbf(xc.z, xc.w);
        float e0 = xa.x - lo16f(h0);
        float e1 = xa.y - hi16f(h0);
        float e2 = xa.z - lo16f(h1);
        float e3 = xa.w - hi16f(h1);
        float e4 = xc.x - lo16f(h2);
        float e5 = xc.y - hi16f(h2);
        float e6 = xc.z - lo16f(h3);
        float e7 = xc.w - hi16f(h3);
        i32x4 ahi = {h0, h1, h2, h3};
        i32x4 alo = {pkbf(e0, e1), pkbf(e2, e3), pkbf(e4, e5), pkbf(e6, e7)};
        bf16x8 AH = asbf(ahi), AL = asbf(alo);
        int tix = tbase + ks * 512;
        #pragma unroll
        for (int ct = 0; ct < 4; ++ct) {
            i32x4 bh = tb[tix + ct * 128];
            i32x4 bl = tb[tix + ct * 128 + 1];
            bf16x8 BH = asbf(bh), BL = asbf(bl);
            acc[ct] = MFMA(AH, BH, acc[ct]);
            acc[ct] = MFMA(AL, BH, acc[ct]);
            acc[ct] = MFMA(AH, BL, acc[ct]);
            bf16x8 BH2 = asbf(bh ^ SM), BL2 = asbf(bl ^ SM);
            acc[ct + 4] = MFMA(AH, BH2, acc[ct + 4]);
            acc[ct + 4] = MFMA(AL, BH2, acc[ct + 4]);
            acc[ct + 4] = MFMA(AH, BL2, acc[ct + 4]);
        }
    }
    int crow = (lane >> 4) << 2;
    int ccol = lane & 15;
    #pragma unroll
    for (int ct = 0; ct < 8; ++ct)
        #pragma unroll
        for (int r = 0; r < 4; ++r)
            sP[w][crow + r][ct * 16 + ccol] = acc[ct][r];
    __syncthreads();
    #pragma unroll
    for (int i = 0; i < 8; ++i) {
        int e = threadIdx.x + 256 * i;     // 0..2047
        int rr = e >> 7, cc = e & 127;
        float s = sP[0][rr][cc] + sP[1][rr][cc] + sP[2][rr][cc] + sP[3][rr][cc];
        xfrp[((size_t)(lseg * 2048 + r0 + rr)) * 128 + cc] = s;
    }
}

// mode mixing -> AF rows 0..127 (per b)
__global__ __launch_bounds__(64) void k_mix(const float* __restrict__ xfrp,
        const float* __restrict__ wpos, const float* __restrict__ wneg,
        const float* __restrict__ phi, float* __restrict__ afull) {
    __shared__ float xr[64], xi[64];
    int bi = blockIdx.x;
    int b = bi >> 6, rem = bi & 63, mm = rem >> 1, side = rem & 1;
    int o = threadIdx.x;
    int slot = side ? (31 - mm) : mm;
    size_t base = (size_t)(b * 64 + o) * 128;
    float vr = 0.f, vi = 0.f;
    if (!side) {
        #pragma unroll
        for (int s = 0; s < 4; ++s) {
            vr += xfrp[(size_t)s * 262144 + base + mm];
            vi += xfrp[(size_t)s * 262144 + base + 32 + mm];
        }
        xr[o] = vr; xi[o] = -vi;
    } else {
        #pragma unroll
        for (int s = 0; s < 4; ++s) {
            vr += xfrp[(size_t)s * 262144 + base + 64 + slot];
            vi += xfrp[(size_t)s * 262144 + base + 96 + slot];
        }
        xr[o] = vr; xi[o] = vi;
    }
    __syncthreads();
    const float* W = side ? wneg : wpos;
    float sre = 0.f, sim = 0.f;
    #pragma unroll 8
    for (int i = 0; i < 64; ++i) {
        float2 w = *(const float2*)&W[((size_t)(i * 64 + o) * 32 + mm) * 2];
        float xri = xr[i], xii = xi[i];
        sre += xri * w.x - xii * w.y;
        sim += xri * w.y + xii * w.x;
    }
    const float* ph = &phi[(b * 32 + mm) * 4 + (side ? 2 : 0)];
    float phr = ph[0], phim = ph[1];
    float Pre = sre * phr - sim * phim;
    float Pim = sre * phim + sim * phr;
    const float invL = 1.f / (float)L_;
    float fac = (slot == 0) ? invL : 2.f * invL;
    float a = fac * Pre;
    float bcoef = (slot == 0) ? 0.f : (side ? 2.f * invL * Pim : -2.f * invL * Pim);
    int comp = side ? 2 : 0;
    afull[((size_t)b * 128 + comp * 32 + slot) * 64 + o] = a;
    afull[((size_t)b * 128 + (comp + 1) * 32 + slot) * 64 + o] = bcoef;
}

// fold coefficients into MFMA A-frag table: ks 0..1 = A0, 2..3 = A1, 4..5 = Ax
__global__ __launch_bounds__(256) void k_folda(const float* __restrict__ lw,
        const float* __restrict__ lb, const float* __restrict__ gb,
        const float* __restrict__ af, ushort* __restrict__ afb, float* __restrict__ bias2) {
    int b = blockIdx.x, tid = threadIdx.x;
    const float* afs = af + (size_t)b * 128 * 64;
    ushort* dst = afb + (size_t)b * 24576;
    #pragma unroll
    for (int j = 0; j < 48; ++j) {
        int u = tid + 256 * j;   // 0..12287 : [ks 6][mt 4][lane 64][e 8]
        int e = u & 7, lane = (u >> 3) & 63, mt = (u >> 9) & 3, ks = u >> 11;
        int c = mt * 16 + (lane & 15);
        int kk = ((lane >> 4) << 3) + e;
        float v = (ks < 4) ? afs[(ks * 32 + kk) * 64 + c]
                           : lw[c * 64 + (ks - 4) * 32 + kk] * gb[(b * 64 + c) * 2];
        ushort hi = f2bf(v);
        ushort lo = f2bf(v - bf2f(hi));
        int base = ((ks * 4 + mt) * 64 + lane) * 16;
        dst[base + e] = hi;
        dst[base + 8 + e] = lo;
    }
    if (tid < 64) {
        float g1 = gb[(b * 64 + tid) * 2], be = gb[(b * 64 + tid) * 2 + 1];
        bias2[b * 64 + tid] = lb[tid] * g1 + be;
    }
}

// MFMA epilogue GEMM: out[b][c][l] = silu( sum_k A[k][c] * B[k][l] + bias2[c] ),
// B = [T(64); (-1)^l T(64); x[b](64)]. grid 1024 = b(32) x lt(32); wave: 64c x 64l.
__global__ __launch_bounds__(256) void k_fuse(const float* __restrict__ x,
        const ushort* __restrict__ TFB, const ushort* __restrict__ AFB,
        const float* __restrict__ bias2, float* __restrict__ out) {
    int b = blockIdx.x >> 5, lt = blockIdx.x & 31;
    int w = threadIdx.x >> 6, lane = threadIdx.x & 63;
    int col = lane & 15, kgrp = lane >> 4;
    int lbase = lt * 256 + w * 64;
    int lt0 = lbase >> 4;
    const i32x4* tb = (const i32x4*)TFB;
    const i32x4* ab = (const i32x4*)AFB + (size_t)b * 3072;

    f32x4 acc[4][4];
    #pragma unroll
    for (int i = 0; i < 4; ++i)
        #pragma unroll
        for (int j = 0; j < 4; ++j) acc[i][j] = (f32x4){0.f, 0.f, 0.f, 0.f};

    int sm = (col & 1) ? (int)0x80008000 : 0;
    i32x4 SM = {sm, sm, sm, sm};

    #pragma unroll
    for (int ts = 0; ts < 2; ++ts) {
        i32x4 bh[4], bl[4];
        #pragma unroll
        for (int nj = 0; nj < 4; ++nj) {
            int tix = (((lt0 + nj) * 2 + ts) * 64 + lane) * 2;
            bh[nj] = tb[tix]; bl[nj] = tb[tix + 1];
        }
        #pragma unroll
        for (int mt = 0; mt < 4; ++mt) {
            int a0 = ((ts * 4 + mt) * 64 + lane) * 2;
            int a1 = (((2 + ts) * 4 + mt) * 64 + lane) * 2;
            i32x4 ah0 = ab[a0], al0 = ab[a0 + 1];
            i32x4 ah1 = ab[a1], al1 = ab[a1 + 1];
            bf16x8 AH0 = asbf(ah0), AL0 = asbf(al0), AH1 = asbf(ah1), AL1 = asbf(al1);
            #pragma unroll
            for (int nj = 0; nj < 4; ++nj) {
                bf16x8 BH = asbf(bh[nj]), BL = asbf(bl[nj]);
                acc[mt][nj] = MFMA(AH0, BH, acc[mt][nj]);
                acc[mt][nj] = MFMA(AL0, BH, acc[mt][nj]);
                acc[mt][nj] = MFMA(AH0, BL, acc[mt][nj]);
                bf16x8 BH2 = asbf(bh[nj] ^ SM), BL2 = asbf(bl[nj] ^ SM);
                acc[mt][nj] = MFMA(AH1, BH2, acc[mt][nj]);
                acc[mt][nj] = MFMA(AL1, BH2, acc[mt][nj]);
                acc[mt][nj] = MFMA(AH1, BL2, acc[mt][nj]);
            }
        }
    }
    #pragma unroll
    for (int ts = 0; ts < 2; ++ts) {
        i32x4 xh[4], xl[4];
        #pragma unroll
        for (int nj = 0; nj < 4; ++nj) {
            const float* xp = x + (size_t)(b * 64 + ts * 32 + kgrp * 8) * L_ + lbase + nj * 16 + col;
            float xv[8];
            #pragma unroll
            for (int e = 0; e < 8; ++e) xv[e] = xp[(size_t)e * L_];
            int h0 = pkbf(xv[0], xv[1]), h1 = pkbf(xv[2], xv[3]);
            int h2 = pkbf(xv[4], xv[5]), h3 = pkbf(xv[6], xv[7]);
            float r0 = xv[0] - lo16f(h0), r1 = xv[1] - hi16f(h0);
            float r2 = xv[2] - lo16f(h1), r3 = xv[3] - hi16f(h1);
            float r4 = xv[4] - lo16f(h2), r5 = xv[5] - hi16f(h2);
            float r6 = xv[6] - lo16f(h3), r7 = xv[7] - hi16f(h3);
            xh[nj] = (i32x4){h0, h1, h2, h3};
            xl[nj] = (i32x4){pkbf(r0, r1), pkbf(r2, r3), pkbf(r4, r5), pkbf(r6, r7)};
        }
        #pragma unroll
        for (int mt = 0; mt < 4; ++mt) {
            int a = (((4 + ts) * 4 + mt) * 64 + lane) * 2;
            i32x4 ah = ab[a], al = ab[a + 1];
            bf16x8 AH = asbf(ah), AL = asbf(al);
            #pragma unroll
            for (int nj = 0; nj < 4; ++nj) {
                bf16x8 XH = asbf(xh[nj]), XL = asbf(xl[nj]);
                acc[mt][nj] = MFMA(AH, XH, acc[mt][nj]);
                acc[mt][nj] = MFMA(AL, XH, acc[mt][nj]);
                acc[mt][nj] = MFMA(AH, XL, acc[mt][nj]);
            }
        }
    }
    #pragma unroll
    for (int mt = 0; mt < 4; ++mt) {
        #pragma unroll
        for (int r = 0; r < 4; ++r) {
            int c = mt * 16 + kgrp * 4 + r;
            float bias = bias2[b * 64 + c];
            float* op = out + (size_t)(b * 64 + c) * L_ + lbase + col;
            #pragma unroll
            for (int nj = 0; nj < 4; ++nj) {
                float v = acc[mt][nj][r] + bias;
                op[nj * 16] = v / (1.f + __expf(-v));
            }
        }
    }
}

extern "C" void kernel_launch(void* const* d_in, const int* in_sizes, int n_in,
                              void* d_out, int out_size, void* d_ws, size_t ws_size,
                              hipStream_t stream) {
    const float* x    = (const float*)d_in[0];
    const float* emb  = (const float*)d_in[1];
    const float* wpos = (const float*)d_in[2];
    const float* wneg = (const float*)d_in[3];
    const float* Arp  = (const float*)d_in[4];
    const float* Aip  = (const float*)d_in[5];
    const float* Arn  = (const float*)d_in[6];
    const float* Ain  = (const float*)d_in[7];
    const float* w1   = (const float*)d_in[8];
    const float* b1   = (const float*)d_in[9];
    const float* w2   = (const float*)d_in[10];
    const float* b2   = (const float*)d_in[11];
    const float* lw   = (const float*)d_in[12];
    const float* lb   = (const float*)d_in[13];
    float* out = (float*)d_out;
    float* ws = (float*)d_ws;
    ushort* TFB  = (ushort*)(ws + OFF_TFB);
    ushort* TLB  = (ushort*)(ws + OFF_TLB);
    ushort* AFB  = (ushort*)(ws + OFF_AFB);
    float*  XFRP = ws + OFF_XFRP;
    float*  AF   = ws + OFF_AF;
    float*  B2   = ws + OFF_B2;
    float*  PHI  = ws + OFF_PHI;
    float*  GB   = ws + OFF_GB;

    hipLaunchKernelGGL(k_trig2, dim3(8192), dim3(256), 0, stream, TLB, TFB);
    hipLaunchKernelGGL(k_phi,   dim3(16),   dim3(256), 0, stream, emb, Arp, Aip, Arn, Ain, PHI);
    hipLaunchKernelGGL(k_mlp,   dim3(32),   dim3(128), 0, stream, emb, w1, b1, w2, b2, GB);
    hipLaunchKernelGGL(k_dft,   dim3(512),  dim3(256), 0, stream, x, TLB, XFRP);
    hipLaunchKernelGGL(k_mix,   dim3(2048), dim3(64),  0, stream, XFRP, wpos, wneg, PHI, AF);
    hipLaunchKernelGGL(k_folda, dim3(32),   dim3(256), 0, stream, lw, lb, GB, AF, AFB, B2);
    hipLaunchKernelGGL(k_fuse,  dim3(1024), dim3(256), 0, stream, x, TFB, AFB, B2, out);
}

// Round 9
// 106.938 us; speedup vs baseline: 3.6097x; 1.2336x over previous
//
#include <hip/hip_runtime.h>
#include <math.h>

#define L_ 8192
#define EMB_ 256
#define HID_ 64

typedef __attribute__((ext_vector_type(8))) short bf16x8;
typedef __attribute__((ext_vector_type(4))) float f32x4;
typedef __attribute__((ext_vector_type(4))) int i32x4;

// workspace layout (floats)
#define OFF_TFB  0           // ushort[512][2][64][16] synthesis B-frag table (2 MB)
#define OFF_TLB  524288      // ushort[256][4][64][16] analysis B-frag table (dead after k_dft)
#define OFF_AFB  524288      // ushort[32][6][4][64][16] A-frag table (aliases TLB; written by k_folda)
#define OFF_XFRP 1048576     // float[4][128][2048] per-Kseg DFT partials, TRANSPOSED (col-major rows)
#define OFF_AF   2097152     // float[32][128][64]  mix output rows
#define OFF_B2   2359296     // float[32*64]
#define OFF_PHI  2361344     // float[32*32*4]
#define OFF_GB   2365440     // float2[32*64]

__device__ inline int pkbf(float a, float b) {
    int r;
    asm volatile("v_cvt_pk_bf16_f32 %0, %1, %2" : "=v"(r) : "v"(a), "v"(b));
    return r;
}
__device__ inline bf16x8 asbf(i32x4 v) { union { i32x4 i; bf16x8 h; } u; u.i = v; return u.h; }
#define MFMA(A,B,C) __builtin_amdgcn_mfma_f32_16x16x32_bf16((A),(B),(C),0,0,0)

__device__ inline ushort f2bf(float v) {
    unsigned b = __float_as_uint(v);
    return (ushort)((b + 0x7FFFu + ((b >> 16) & 1u)) >> 16);
}
__device__ inline float bf2f(ushort h) { return __uint_as_float(((unsigned)h) << 16); }
__device__ inline float lo16f(int h) { return __uint_as_float(((unsigned)h) << 16); }
__device__ inline float hi16f(int h) { return __uint_as_float(((unsigned)h) & 0xFFFF0000u); }

// TLB: analysis frags [kstep 256][ct 4][lane 64][e16]; TFB: synthesis frags [ltile 512][ts 2][lane 64][e16]
__global__ __launch_bounds__(256) void k_trig2(ushort* __restrict__ TLB, ushort* __restrict__ TFB) {
    int idx = blockIdx.x * 256 + threadIdx.x;   // 0..2097151
    int f, l; ushort* dst; bool lohalf;
    if (idx < 1048576) {
        int u = idx;
        int e = u & 15, lane = (u >> 4) & 63, ct = (u >> 10) & 3, kstep = u >> 12;
        l = kstep * 32 + ((lane >> 4) << 3) + (e & 7);
        int colf = ct * 16 + (lane & 15);
        f = colf;                                // 0..31 cos, 32..63 sin
        dst = TLB + u; lohalf = (e >= 8);
    } else {
        int u = idx - 1048576;
        int e = u & 15, lane = (u >> 4) & 63, ts = (u >> 10) & 1, lt = u >> 11;
        l = lt * 16 + (lane & 15);
        f = ts * 32 + ((lane >> 4) << 3) + (e & 7);
        dst = TFB + u; lohalf = (e >= 8);
    }
    int fr = f & 31; bool sinp = (f & 32) != 0;
    int r = (fr * l) & (L_ - 1);
    float ang = (float)r * (6.283185307179586f / (float)L_);
    float v = sinp ? sinf(ang) : cosf(ang);
    ushort hi = f2bf(v);
    *dst = lohalf ? f2bf(v - bf2f(hi)) : hi;
}

__global__ __launch_bounds__(256) void k_phi(const float* __restrict__ emb,
        const float* __restrict__ Arp, const float* __restrict__ Aip,
        const float* __restrict__ Arn, const float* __restrict__ Ain,
        float* __restrict__ phi) {
    int tid = blockIdx.x * 256 + threadIdx.x;   // (b*32+mm)*4+cmp
    int b = tid >> 7;
    int mm = (tid >> 2) & 31;
    int cmp = tid & 3;
    const float* A = (cmp == 0) ? Arp : (cmp == 1) ? Aip : (cmp == 2) ? Arn : Ain;
    const float4* e4 = (const float4*)(emb + b * EMB_);
    const float4* a4 = (const float4*)(A + mm * EMB_);
    float acc = 0.f;
    for (int q = 0; q < EMB_ / 4; ++q) {
        float4 ev = e4[q], av = a4[q];
        acc += ev.x * av.x + ev.y * av.y + ev.z * av.z + ev.w * av.w;
    }
    phi[tid] = acc;
}

__global__ __launch_bounds__(128) void k_mlp(const float* __restrict__ emb,
        const float* __restrict__ w1, const float* __restrict__ b1,
        const float* __restrict__ w2, const float* __restrict__ b2,
        float* __restrict__ gb) {
    __shared__ float h[HID_];
    int b = blockIdx.x, t = threadIdx.x;
    if (t < HID_) {
        const float4* e4 = (const float4*)(emb + b * EMB_);
        const float4* w4 = (const float4*)(w1 + t * EMB_);
        float acc = b1[t];
        for (int q = 0; q < EMB_ / 4; ++q) {
            float4 ev = e4[q], wv = w4[q];
            acc += ev.x * wv.x + ev.y * wv.y + ev.z * wv.z + ev.w * wv.w;
        }
        h[t] = acc / (1.f + expf(-acc));
    }
    __syncthreads();
    float g = b2[t];
    const float4* h4 = (const float4*)h;
    const float4* w4 = (const float4*)(w2 + t * HID_);
    for (int q = 0; q < HID_ / 4; ++q) {
        float4 hv = h4[q], wv = w4[q];
        g += hv.x * wv.x + hv.y * wv.y + hv.z * wv.z + hv.w * wv.w;
    }
    if (t < 64) gb[(b * 64 + t) * 2 + 0] = 1.f + g;
    else        gb[(b * 64 + (t - 64)) * 2 + 1] = g;
}

// split-bf16 MFMA DFT; stores TRANSPOSED partials xfrp[lseg][col][row]
__global__ __launch_bounds__(256) void k_dft(const float* __restrict__ x,
        const ushort* __restrict__ TLB, float* __restrict__ xfrp) {
    __shared__ float sP[4][16][132];
    int stripe = blockIdx.x >> 2;
    int lseg = blockIdx.x & 3;
    int w = threadIdx.x >> 6;
    int lane = threadIdx.x & 63;
    int row = lane & 15, koff = (lane >> 4) << 3;
    int r0 = stripe * 16;
    int kb0 = lseg * 2048 + w * 512;

    f32x4 acc[8];
    #pragma unroll
    for (int i = 0; i < 8; ++i) acc[i] = (f32x4){0.f, 0.f, 0.f, 0.f};

    const float* ap = x + (size_t)(r0 + row) * L_ + kb0 + koff;
    const i32x4* tb = (const i32x4*)TLB;
    int tbase = (((kb0 >> 5) * 4) * 64 + lane) * 2;      // +512 per kstep
    const i32x4 SM = {(int)0x80000000, (int)0x80000000, (int)0x80000000, (int)0x80000000};

    for (int ks = 0; ks < 16; ++ks) {
        float4 xa = *(const float4*)(ap + ks * 32);
        float4 xc = *(const float4*)(ap + ks * 32 + 4);
        int h0 = pkbf(xa.x, xa.y), h1 = pkbf(xa.z, xa.w);
        int h2 = pkbf(xc.x, xc.y), h3 = pkbf(xc.z, xc.w);
        float e0 = xa.x - lo16f(h0);
        float e1 = xa.y - hi16f(h0);
        float e2 = xa.z - lo16f(h1);
        float e3 = xa.w - hi16f(h1);
        float e4 = xc.x - lo16f(h2);
        float e5 = xc.y - hi16f(h2);
        float e6 = xc.z - lo16f(h3);
        float e7 = xc.w - hi16f(h3);
        i32x4 ahi = {h0, h1, h2, h3};
        i32x4 alo = {pkbf(e0, e1), pkbf(e2, e3), pkbf(e4, e5), pkbf(e6, e7)};
        bf16x8 AH = asbf(ahi), AL = asbf(alo);
        int tix = tbase + ks * 512;
        #pragma unroll
        for (int ct = 0; ct < 4; ++ct) {
            i32x4 bh = tb[tix + ct * 128];
            i32x4 bl = tb[tix + ct * 128 + 1];
            bf16x8 BH = asbf(bh), BL = asbf(bl);
            acc[ct] = MFMA(AH, BH, acc[ct]);
            acc[ct] = MFMA(AL, BH, acc[ct]);
            acc[ct] = MFMA(AH, BL, acc[ct]);
            bf16x8 BH2 = asbf(bh ^ SM), BL2 = asbf(bl ^ SM);
            acc[ct + 4] = MFMA(AH, BH2, acc[ct + 4]);
            acc[ct + 4] = MFMA(AL, BH2, acc[ct + 4]);
            acc[ct + 4] = MFMA(AH, BL2, acc[ct + 4]);
        }
    }
    int crow = (lane >> 4) << 2;
    int ccol = lane & 15;
    #pragma unroll
    for (int ct = 0; ct < 8; ++ct)
        #pragma unroll
        for (int r = 0; r < 4; ++r)
            sP[w][crow + r][ct * 16 + ccol] = acc[ct][r];
    __syncthreads();
    #pragma unroll
    for (int i = 0; i < 8; ++i) {
        int e = threadIdx.x + 256 * i;     // 0..2047
        int rr = e & 15, cc = e >> 4;
        float s = sP[0][rr][cc] + sP[1][rr][cc] + sP[2][rr][cc] + sP[3][rr][cc];
        xfrp[((size_t)(lseg * 128 + cc)) * 2048 + r0 + rr] = s;
    }
}

// mode mixing -> AF rows 0..127. grid 128 = [mm 32][side 2][bh 2]; 256 thr = bg(4) x o(64)
__global__ __launch_bounds__(256) void k_mix(const float* __restrict__ xfrt,
        const float* __restrict__ wpos, const float* __restrict__ wneg,
        const float* __restrict__ phi, float* __restrict__ afull) {
    __shared__ float sW[64][64][2];     // [i][o][re/im]
    __shared__ float sXr[16][64], sXi[16][64];   // [b_local][i]
    int bi = blockIdx.x;
    int bh = bi & 1, side = (bi >> 1) & 1, mm = bi >> 2;
    int tid = threadIdx.x;
    int slot = side ? (31 - mm) : mm;
    int colR = side ? (64 + slot) : mm;
    int colI = side ? (96 + slot) : (32 + mm);

    // stage W tile (gather once per block)
    const float* W = side ? wneg : wpos;
    #pragma unroll
    for (int j = 0; j < 16; ++j) {
        int fidx = tid + 256 * j;       // 0..4095 = i*64+o
        int i = fidx >> 6, o = fidx & 63;
        float2 wv = *(const float2*)&W[(size_t)(i * 64 + o) * 64 + mm * 2];
        sW[i][o][0] = wv.x;
        sW[i][o][1] = wv.y;
    }
    // stage slab-summed x rows (coalesced)
    {
        const float4* pR = (const float4*)(xfrt + (size_t)colR * 2048 + bh * 1024);
        const float4* pI = (const float4*)(xfrt + (size_t)colI * 2048 + bh * 1024);
        float4 aR = {0, 0, 0, 0}, aI = {0, 0, 0, 0};
        #pragma unroll
        for (int s = 0; s < 4; ++s) {
            float4 vR = pR[(size_t)s * 65536 + tid];
            float4 vI = pI[(size_t)s * 65536 + tid];
            aR.x += vR.x; aR.y += vR.y; aR.z += vR.z; aR.w += vR.w;
            aI.x += vI.x; aI.y += vI.y; aI.z += vI.z; aI.w += vI.w;
        }
        if (!side) { aI.x = -aI.x; aI.y = -aI.y; aI.z = -aI.z; aI.w = -aI.w; }
        *(float4*)&sXr[tid >> 4][(tid & 15) * 4] = aR;
        *(float4*)&sXi[tid >> 4][(tid & 15) * 4] = aI;
    }
    __syncthreads();

    int o = tid & 63, bg = tid >> 6;
    const float invL = 1.f / (float)L_;
    float fac = (slot == 0) ? invL : 2.f * invL;
    int comp = side ? 2 : 0;
    #pragma unroll
    for (int bl = 0; bl < 4; ++bl) {
        int b_local = bg * 4 + bl;
        int b = bh * 16 + b_local;
        float sre = 0.f, sim = 0.f;
        #pragma unroll 16
        for (int i = 0; i < 64; ++i) {
            float wr = sW[i][o][0], wi = sW[i][o][1];
            float xr = sXr[b_local][i], xi = sXi[b_local][i];
            sre += xr * wr - xi * wi;
            sim += xr * wi + xi * wr;
        }
        const float* ph = &phi[(b * 32 + mm) * 4 + (side ? 2 : 0)];
        float phr = ph[0], phim = ph[1];
        float Pre = sre * phr - sim * phim;
        float Pim = sre * phim + sim * phr;
        float a = fac * Pre;
        float bcoef = (slot == 0) ? 0.f : (side ? 2.f * invL * Pim : -2.f * invL * Pim);
        afull[((size_t)b * 128 + comp * 32 + slot) * 64 + o] = a;
        afull[((size_t)b * 128 + (comp + 1) * 32 + slot) * 64 + o] = bcoef;
    }
}

// fold coefficients into MFMA A-frag table: ks 0..1 = A0, 2..3 = A1, 4..5 = Ax
__global__ __launch_bounds__(256) void k_folda(const float* __restrict__ lw,
        const float* __restrict__ lb, const float* __restrict__ gb,
        const float* __restrict__ af, ushort* __restrict__ afb, float* __restrict__ bias2) {
    int b = blockIdx.x, tid = threadIdx.x;
    const float* afs = af + (size_t)b * 128 * 64;
    ushort* dst = afb + (size_t)b * 24576;
    #pragma unroll
    for (int j = 0; j < 48; ++j) {
        int u = tid + 256 * j;   // 0..12287 : [ks 6][mt 4][lane 64][e 8]
        int e = u & 7, lane = (u >> 3) & 63, mt = (u >> 9) & 3, ks = u >> 11;
        int c = mt * 16 + (lane & 15);
        int kk = ((lane >> 4) << 3) + e;
        float v = (ks < 4) ? afs[(ks * 32 + kk) * 64 + c]
                           : lw[c * 64 + (ks - 4) * 32 + kk] * gb[(b * 64 + c) * 2];
        ushort hi = f2bf(v);
        ushort lo = f2bf(v - bf2f(hi));
        int base = ((ks * 4 + mt) * 64 + lane) * 16;
        dst[base + e] = hi;
        dst[base + 8 + e] = lo;
    }
    if (tid < 64) {
        float g1 = gb[(b * 64 + tid) * 2], be = gb[(b * 64 + tid) * 2 + 1];
        bias2[b * 64 + tid] = lb[tid] * g1 + be;
    }
}

// MFMA epilogue GEMM: out[b][c][l] = silu( sum_k A[k][c] * B[k][l] + bias2[c] ),
// B = [T(64); (-1)^l T(64); x[b](64)]. grid 1024 = b(32) x lt(32); wave: 64c x 64l.
__global__ __launch_bounds__(256) void k_fuse(const float* __restrict__ x,
        const ushort* __restrict__ TFB, const ushort* __restrict__ AFB,
        const float* __restrict__ bias2, float* __restrict__ out) {
    int b = blockIdx.x >> 5, lt = blockIdx.x & 31;
    int w = threadIdx.x >> 6, lane = threadIdx.x & 63;
    int col = lane & 15, kgrp = lane >> 4;
    int lbase = lt * 256 + w * 64;
    int lt0 = lbase >> 4;
    const i32x4* tb = (const i32x4*)TFB;
    const i32x4* ab = (const i32x4*)AFB + (size_t)b * 3072;

    f32x4 acc[4][4];
    #pragma unroll
    for (int i = 0; i < 4; ++i)
        #pragma unroll
        for (int j = 0; j < 4; ++j) acc[i][j] = (f32x4){0.f, 0.f, 0.f, 0.f};

    int sm = (col & 1) ? (int)0x80008000 : 0;
    i32x4 SM = {sm, sm, sm, sm};

    #pragma unroll
    for (int ts = 0; ts < 2; ++ts) {
        i32x4 bh[4], bl[4];
        #pragma unroll
        for (int nj = 0; nj < 4; ++nj) {
            int tix = (((lt0 + nj) * 2 + ts) * 64 + lane) * 2;
            bh[nj] = tb[tix]; bl[nj] = tb[tix + 1];
        }
        #pragma unroll
        for (int mt = 0; mt < 4; ++mt) {
            int a0 = ((ts * 4 + mt) * 64 + lane) * 2;
            int a1 = (((2 + ts) * 4 + mt) * 64 + lane) * 2;
            i32x4 ah0 = ab[a0], al0 = ab[a0 + 1];
            i32x4 ah1 = ab[a1], al1 = ab[a1 + 1];
            bf16x8 AH0 = asbf(ah0), AL0 = asbf(al0), AH1 = asbf(ah1), AL1 = asbf(al1);
            #pragma unroll
            for (int nj = 0; nj < 4; ++nj) {
                bf16x8 BH = asbf(bh[nj]), BL = asbf(bl[nj]);
                acc[mt][nj] = MFMA(AH0, BH, acc[mt][nj]);
                acc[mt][nj] = MFMA(AL0, BH, acc[mt][nj]);
                acc[mt][nj] = MFMA(AH0, BL, acc[mt][nj]);
                bf16x8 BH2 = asbf(bh[nj] ^ SM), BL2 = asbf(bl[nj] ^ SM);
                acc[mt][nj] = MFMA(AH1, BH2, acc[mt][nj]);
                acc[mt][nj] = MFMA(AL1, BH2, acc[mt][nj]);
                acc[mt][nj] = MFMA(AH1, BL2, acc[mt][nj]);
            }
        }
    }
    #pragma unroll
    for (int ts = 0; ts < 2; ++ts) {
        i32x4 xh[4], xl[4];
        #pragma unroll
        for (int nj = 0; nj < 4; ++nj) {
            const float* xp = x + (size_t)(b * 64 + ts * 32 + kgrp * 8) * L_ + lbase + nj * 16 + col;
            float xv[8];
            #pragma unroll
            for (int e = 0; e < 8; ++e) xv[e] = xp[(size_t)e * L_];
            int h0 = pkbf(xv[0], xv[1]), h1 = pkbf(xv[2], xv[3]);
            int h2 = pkbf(xv[4], xv[5]), h3 = pkbf(xv[6], xv[7]);
            float r0 = xv[0] - lo16f(h0), r1 = xv[1] - hi16f(h0);
            float r2 = xv[2] - lo16f(h1), r3 = xv[3] - hi16f(h1);
            float r4 = xv[4] - lo16f(h2), r5 = xv[5] - hi16f(h2);
            float r6 = xv[6] - lo16f(h3), r7 = xv[7] - hi16f(h3);
            xh[nj] = (i32x4){h0, h1, h2, h3};
            xl[nj] = (i32x4){pkbf(r0, r1), pkbf(r2, r3), pkbf(r4, r5), pkbf(r6, r7)};
        }
        #pragma unroll
        for (int mt = 0; mt < 4; ++mt) {
            int a = (((4 + ts) * 4 + mt) * 64 + lane) * 2;
            i32x4 ah = ab[a], al = ab[a + 1];
            bf16x8 AH = asbf(ah), AL = asbf(al);
            #pragma unroll
            for (int nj = 0; nj < 4; ++nj) {
                bf16x8 XH = asbf(xh[nj]), XL = asbf(xl[nj]);
                acc[mt][nj] = MFMA(AH, XH, acc[mt][nj]);
                acc[mt][nj] = MFMA(AL, XH, acc[mt][nj]);
                acc[mt][nj] = MFMA(AH, XL, acc[mt][nj]);
            }
        }
    }
    #pragma unroll
    for (int mt = 0; mt < 4; ++mt) {
        #pragma unroll
        for (int r = 0; r < 4; ++r) {
            int c = mt * 16 + kgrp * 4 + r;
            float bias = bias2[b * 64 + c];
            float* op = out + (size_t)(b * 64 + c) * L_ + lbase + col;
            #pragma unroll
            for (int nj = 0; nj < 4; ++nj) {
                float v = acc[mt][nj][r] + bias;
                op[nj * 16] = v / (1.f + __expf(-v));
            }
        }
    }
}

extern "C" void kernel_launch(void* const* d_in, const int* in_sizes, int n_in,
                              void* d_out, int out_size, void* d_ws, size_t ws_size,
                              hipStream_t stream) {
    const float* x    = (const float*)d_in[0];
    const float* emb  = (const float*)d_in[1];
    const float* wpos = (const float*)d_in[2];
    const float* wneg = (const float*)d_in[3];
    const float* Arp  = (const float*)d_in[4];
    const float* Aip  = (const float*)d_in[5];
    const float* Arn  = (const float*)d_in[6];
    const float* Ain  = (const float*)d_in[7];
    const float* w1   = (const float*)d_in[8];
    const float* b1   = (const float*)d_in[9];
    const float* w2   = (const float*)d_in[10];
    const float* b2   = (const float*)d_in[11];
    const float* lw   = (const float*)d_in[12];
    const float* lb   = (const float*)d_in[13];
    float* out = (float*)d_out;
    float* ws = (float*)d_ws;
    ushort* TFB  = (ushort*)(ws + OFF_TFB);
    ushort* TLB  = (ushort*)(ws + OFF_TLB);
    ushort* AFB  = (ushort*)(ws + OFF_AFB);
    float*  XFRP = ws + OFF_XFRP;
    float*  AF   = ws + OFF_AF;
    float*  B2   = ws + OFF_B2;
    float*  PHI  = ws + OFF_PHI;
    float*  GB   = ws + OFF_GB;

    hipLaunchKernelGGL(k_trig2, dim3(8192), dim3(256), 0, stream, TLB, TFB);
    hipLaunchKernelGGL(k_phi,   dim3(16),   dim3(256), 0, stream, emb, Arp, Aip, Arn, Ain, PHI);
    hipLaunchKernelGGL(k_mlp,   dim3(32),   dim3(128), 0, stream, emb, w1, b1, w2, b2, GB);
    hipLaunchKernelGGL(k_dft,   dim3(512),  dim3(256), 0, stream, x, TLB, XFRP);
    hipLaunchKernelGGL(k_mix,   dim3(128),  dim3(256), 0, stream, XFRP, wpos, wneg, PHI, AF);
    hipLaunchKernelGGL(k_folda, dim3(32),   dim3(256), 0, stream, lw, lb, GB, AF, AFB, B2);
    hipLaunchKernelGGL(k_fuse,  dim3(1024), dim3(256), 0, stream, x, TFB, AFB, B2, out);
}

// Round 10
// 102.885 us; speedup vs baseline: 3.7519x; 1.0394x over previous
//
#include <hip/hip_runtime.h>
#include <math.h>

#define L_ 8192
#define EMB_ 256
#define HID_ 64

typedef __attribute__((ext_vector_type(8))) short bf16x8;
typedef __attribute__((ext_vector_type(4))) float f32x4;
typedef __attribute__((ext_vector_type(4))) int i32x4;

// workspace layout (floats)
#define OFF_TFB  0           // ushort[512][2][64][16] synthesis B-frag table (2 MB)
#define OFF_TLB  524288      // ushort[256][4][64][16] analysis B-frag table (dead after k_dft)
#define OFF_AFB  524288      // ushort[32][6][4][64][16] A-frag table (aliases TLB; written by k_folda)
#define OFF_XFRP 1048576     // float[4][128][2048] per-Kseg DFT partials, TRANSPOSED (col-major rows)
#define OFF_AF   2097152     // float[32][128][64]  mix output rows
#define OFF_B2   2359296     // float[32*64]
#define OFF_PHI  2361344     // float[32*32*4]
#define OFF_GB   2365440     // float2[32*64]

__device__ inline int pkbf(float a, float b) {
    int r;
    asm volatile("v_cvt_pk_bf16_f32 %0, %1, %2" : "=v"(r) : "v"(a), "v"(b));
    return r;
}
__device__ inline bf16x8 asbf(i32x4 v) { union { i32x4 i; bf16x8 h; } u; u.i = v; return u.h; }
#define MFMA(A,B,C) __builtin_amdgcn_mfma_f32_16x16x32_bf16((A),(B),(C),0,0,0)

__device__ inline ushort f2bf(float v) {
    unsigned b = __float_as_uint(v);
    return (ushort)((b + 0x7FFFu + ((b >> 16) & 1u)) >> 16);
}
__device__ inline float bf2f(ushort h) { return __uint_as_float(((unsigned)h) << 16); }
__device__ inline float lo16f(int h) { return __uint_as_float(((unsigned)h) << 16); }
__device__ inline float hi16f(int h) { return __uint_as_float(((unsigned)h) & 0xFFFF0000u); }

// TLB: analysis frags [kstep 256][ct 4][lane 64][e16]; TFB: synthesis frags [ltile 512][ts 2][lane 64][e16]
__global__ __launch_bounds__(256) void k_trig2(ushort* __restrict__ TLB, ushort* __restrict__ TFB) {
    int idx = blockIdx.x * 256 + threadIdx.x;   // 0..2097151
    int f, l; ushort* dst; bool lohalf;
    if (idx < 1048576) {
        int u = idx;
        int e = u & 15, lane = (u >> 4) & 63, ct = (u >> 10) & 3, kstep = u >> 12;
        l = kstep * 32 + ((lane >> 4) << 3) + (e & 7);
        int colf = ct * 16 + (lane & 15);
        f = colf;                                // 0..31 cos, 32..63 sin
        dst = TLB + u; lohalf = (e >= 8);
    } else {
        int u = idx - 1048576;
        int e = u & 15, lane = (u >> 4) & 63, ts = (u >> 10) & 1, lt = u >> 11;
        l = lt * 16 + (lane & 15);
        f = ts * 32 + ((lane >> 4) << 3) + (e & 7);
        dst = TFB + u; lohalf = (e >= 8);
    }
    int fr = f & 31; bool sinp = (f & 32) != 0;
    int r = (fr * l) & (L_ - 1);
    float ang = (float)r * (6.283185307179586f / (float)L_);
    float v = sinp ? sinf(ang) : cosf(ang);
    ushort hi = f2bf(v);
    *dst = lohalf ? f2bf(v - bf2f(hi)) : hi;
}

__global__ __launch_bounds__(256) void k_phi(const float* __restrict__ emb,
        const float* __restrict__ Arp, const float* __restrict__ Aip,
        const float* __restrict__ Arn, const float* __restrict__ Ain,
        float* __restrict__ phi) {
    int tid = blockIdx.x * 256 + threadIdx.x;   // (b*32+mm)*4+cmp
    int b = tid >> 7;
    int mm = (tid >> 2) & 31;
    int cmp = tid & 3;
    const float* A = (cmp == 0) ? Arp : (cmp == 1) ? Aip : (cmp == 2) ? Arn : Ain;
    const float4* e4 = (const float4*)(emb + b * EMB_);
    const float4* a4 = (const float4*)(A + mm * EMB_);
    float acc = 0.f;
    for (int q = 0; q < EMB_ / 4; ++q) {
        float4 ev = e4[q], av = a4[q];
        acc += ev.x * av.x + ev.y * av.y + ev.z * av.z + ev.w * av.w;
    }
    phi[tid] = acc;
}

__global__ __launch_bounds__(128) void k_mlp(const float* __restrict__ emb,
        const float* __restrict__ w1, const float* __restrict__ b1,
        const float* __restrict__ w2, const float* __restrict__ b2,
        float* __restrict__ gb) {
    __shared__ float h[HID_];
    int b = blockIdx.x, t = threadIdx.x;
    if (t < HID_) {
        const float4* e4 = (const float4*)(emb + b * EMB_);
        const float4* w4 = (const float4*)(w1 + t * EMB_);
        float acc = b1[t];
        for (int q = 0; q < EMB_ / 4; ++q) {
            float4 ev = e4[q], wv = w4[q];
            acc += ev.x * wv.x + ev.y * wv.y + ev.z * wv.z + ev.w * wv.w;
        }
        h[t] = acc / (1.f + expf(-acc));
    }
    __syncthreads();
    float g = b2[t];
    const float4* h4 = (const float4*)h;
    const float4* w4 = (const float4*)(w2 + t * HID_);
    for (int q = 0; q < HID_ / 4; ++q) {
        float4 hv = h4[q], wv = w4[q];
        g += hv.x * wv.x + hv.y * wv.y + hv.z * wv.z + hv.w * wv.w;
    }
    if (t < 64) gb[(b * 64 + t) * 2 + 0] = 1.f + g;
    else        gb[(b * 64 + (t - 64)) * 2 + 1] = g;
}

// split-bf16 MFMA DFT; stores TRANSPOSED partials xfrp[lseg][col][row]
__global__ __launch_bounds__(256) void k_dft(const float* __restrict__ x,
        const ushort* __restrict__ TLB, float* __restrict__ xfrp) {
    __shared__ float sP[4][16][132];
    int stripe = blockIdx.x >> 2;
    int lseg = blockIdx.x & 3;
    int w = threadIdx.x >> 6;
    int lane = threadIdx.x & 63;
    int row = lane & 15, koff = (lane >> 4) << 3;
    int r0 = stripe * 16;
    int kb0 = lseg * 2048 + w * 512;

    f32x4 acc[8];
    #pragma unroll
    for (int i = 0; i < 8; ++i) acc[i] = (f32x4){0.f, 0.f, 0.f, 0.f};

    const float* ap = x + (size_t)(r0 + row) * L_ + kb0 + koff;
    const i32x4* tb = (const i32x4*)TLB;
    int tbase = (((kb0 >> 5) * 4) * 64 + lane) * 2;      // +512 per kstep
    const i32x4 SM = {(int)0x80000000, (int)0x80000000, (int)0x80000000, (int)0x80000000};

    for (int ks = 0; ks < 16; ++ks) {
        float4 xa = *(const float4*)(ap + ks * 32);
        float4 xc = *(const float4*)(ap + ks * 32 + 4);
        int h0 = pkbf(xa.x, xa.y), h1 = pkbf(xa.z, xa.w);
        int h2 = pkbf(xc.x, xc.y), h3 = pkbf(xc.z, xc.w);
        float e0 = xa.x - lo16f(h0);
        float e1 = xa.y - hi16f(h0);
        float e2 = xa.z - lo16f(h1);
        float e3 = xa.w - hi16f(h1);
        float e4 = xc.x - lo16f(h2);
        float e5 = xc.y - hi16f(h2);
        float e6 = xc.z - lo16f(h3);
        float e7 = xc.w - hi16f(h3);
        i32x4 ahi = {h0, h1, h2, h3};
        i32x4 alo = {pkbf(e0, e1), pkbf(e2, e3), pkbf(e4, e5), pkbf(e6, e7)};
        bf16x8 AH = asbf(ahi), AL = asbf(alo);
        int tix = tbase + ks * 512;
        #pragma unroll
        for (int ct = 0; ct < 4; ++ct) {
            i32x4 bh = tb[tix + ct * 128];
            i32x4 bl = tb[tix + ct * 128 + 1];
            bf16x8 BH = asbf(bh), BL = asbf(bl);
            acc[ct] = MFMA(AH, BH, acc[ct]);
            acc[ct] = MFMA(AL, BH, acc[ct]);
            acc[ct] = MFMA(AH, BL, acc[ct]);
            bf16x8 BH2 = asbf(bh ^ SM), BL2 = asbf(bl ^ SM);
            acc[ct + 4] = MFMA(AH, BH2, acc[ct + 4]);
            acc[ct + 4] = MFMA(AL, BH2, acc[ct + 4]);
            acc[ct + 4] = MFMA(AH, BL2, acc[ct + 4]);
        }
    }
    int crow = (lane >> 4) << 2;
    int ccol = lane & 15;
    #pragma unroll
    for (int ct = 0; ct < 8; ++ct)
        #pragma unroll
        for (int r = 0; r < 4; ++r)
            sP[w][crow + r][ct * 16 + ccol] = acc[ct][r];
    __syncthreads();
    #pragma unroll
    for (int i = 0; i < 8; ++i) {
        int e = threadIdx.x + 256 * i;     // 0..2047
        int rr = e & 15, cc = e >> 4;
        float s = sP[0][rr][cc] + sP[1][rr][cc] + sP[2][rr][cc] + sP[3][rr][cc];
        xfrp[((size_t)(lseg * 128 + cc)) * 2048 + r0 + rr] = s;
    }
}

// mode mixing -> AF rows 0..127. grid 128 = [mm 32][side 2][bh 2]; 256 thr = bg(4) x o(64)
__global__ __launch_bounds__(256) void k_mix(const float* __restrict__ xfrt,
        const float* __restrict__ wpos, const float* __restrict__ wneg,
        const float* __restrict__ phi, float* __restrict__ afull) {
    __shared__ float sW[64][64][2];     // [i][o][re/im]
    __shared__ float sXr[16][64], sXi[16][64];   // [b_local][i]
    int bi = blockIdx.x;
    int bh = bi & 1, side = (bi >> 1) & 1, mm = bi >> 2;
    int tid = threadIdx.x;
    int slot = side ? (31 - mm) : mm;
    int colR = side ? (64 + slot) : mm;
    int colI = side ? (96 + slot) : (32 + mm);

    // stage W tile (gather once per block)
    const float* W = side ? wneg : wpos;
    #pragma unroll
    for (int j = 0; j < 16; ++j) {
        int fidx = tid + 256 * j;       // 0..4095 = i*64+o
        int i = fidx >> 6, o = fidx & 63;
        float2 wv = *(const float2*)&W[(size_t)(i * 64 + o) * 64 + mm * 2];
        sW[i][o][0] = wv.x;
        sW[i][o][1] = wv.y;
    }
    // stage slab-summed x rows (coalesced)
    {
        const float4* pR = (const float4*)(xfrt + (size_t)colR * 2048 + bh * 1024);
        const float4* pI = (const float4*)(xfrt + (size_t)colI * 2048 + bh * 1024);
        float4 aR = {0, 0, 0, 0}, aI = {0, 0, 0, 0};
        #pragma unroll
        for (int s = 0; s < 4; ++s) {
            float4 vR = pR[(size_t)s * 65536 + tid];
            float4 vI = pI[(size_t)s * 65536 + tid];
            aR.x += vR.x; aR.y += vR.y; aR.z += vR.z; aR.w += vR.w;
            aI.x += vI.x; aI.y += vI.y; aI.z += vI.z; aI.w += vI.w;
        }
        if (!side) { aI.x = -aI.x; aI.y = -aI.y; aI.z = -aI.z; aI.w = -aI.w; }
        *(float4*)&sXr[tid >> 4][(tid & 15) * 4] = aR;
        *(float4*)&sXi[tid >> 4][(tid & 15) * 4] = aI;
    }
    __syncthreads();

    int o = tid & 63, bg = tid >> 6;
    const float invL = 1.f / (float)L_;
    float fac = (slot == 0) ? invL : 2.f * invL;
    int comp = side ? 2 : 0;
    #pragma unroll
    for (int bl = 0; bl < 4; ++bl) {
        int b_local = bg * 4 + bl;
        int b = bh * 16 + b_local;
        float sre = 0.f, sim = 0.f;
        #pragma unroll 16
        for (int i = 0; i < 64; ++i) {
            float wr = sW[i][o][0], wi = sW[i][o][1];
            float xr = sXr[b_local][i], xi = sXi[b_local][i];
            sre += xr * wr - xi * wi;
            sim += xr * wi + xi * wr;
        }
        const float* ph = &phi[(b * 32 + mm) * 4 + (side ? 2 : 0)];
        float phr = ph[0], phim = ph[1];
        float Pre = sre * phr - sim * phim;
        float Pim = sre * phim + sim * phr;
        float a = fac * Pre;
        float bcoef = (slot == 0) ? 0.f : (side ? 2.f * invL * Pim : -2.f * invL * Pim);
        afull[((size_t)b * 128 + comp * 32 + slot) * 64 + o] = a;
        afull[((size_t)b * 128 + (comp + 1) * 32 + slot) * 64 + o] = bcoef;
    }
}

// fold coefficients into MFMA A-frag table: ks 0..1 = A0, 2..3 = A1, 4..5 = Ax
__global__ __launch_bounds__(256) void k_folda(const float* __restrict__ lw,
        const float* __restrict__ lb, const float* __restrict__ gb,
        const float* __restrict__ af, ushort* __restrict__ afb, float* __restrict__ bias2) {
    int b = blockIdx.x, tid = threadIdx.x;
    const float* afs = af + (size_t)b * 128 * 64;
    ushort* dst = afb + (size_t)b * 24576;
    #pragma unroll
    for (int j = 0; j < 48; ++j) {
        int u = tid + 256 * j;   // 0..12287 : [ks 6][mt 4][lane 64][e 8]
        int e = u & 7, lane = (u >> 3) & 63, mt = (u >> 9) & 3, ks = u >> 11;
        int c = mt * 16 + (lane & 15);
        int kk = ((lane >> 4) << 3) + e;
        float v = (ks < 4) ? afs[(ks * 32 + kk) * 64 + c]
                           : lw[c * 64 + (ks - 4) * 32 + kk] * gb[(b * 64 + c) * 2];
        ushort hi = f2bf(v);
        ushort lo = f2bf(v - bf2f(hi));
        int base = ((ks * 4 + mt) * 64 + lane) * 16;
        dst[base + e] = hi;
        dst[base + 8 + e] = lo;
    }
    if (tid < 64) {
        float g1 = gb[(b * 64 + tid) * 2], be = gb[(b * 64 + tid) * 2 + 1];
        bias2[b * 64 + tid] = lb[tid] * g1 + be;
    }
}

// MFMA epilogue GEMM: out[b][c][l] = silu( sum_k A[k][c] * B[k][l] + bias2[c] ),
// B = [T(64); (-1)^l T(64); x[b](64)]. grid 2048 = b(32) x lt(64); wave: 64c x 32l.
// Schedule: issue x-loads(ts) early, T-part MFMAs overlap their latency (T14).
__global__ __launch_bounds__(256, 3) void k_fuse(const float* __restrict__ x,
        const ushort* __restrict__ TFB, const ushort* __restrict__ AFB,
        const float* __restrict__ bias2, float* __restrict__ out) {
    int b = blockIdx.x >> 6, lt = blockIdx.x & 63;
    int w = threadIdx.x >> 6, lane = threadIdx.x & 63;
    int col = lane & 15, kgrp = lane >> 4;
    int lbase = lt * 128 + w * 32;
    int lt0 = lbase >> 4;
    const i32x4* tb = (const i32x4*)TFB;
    const i32x4* ab = (const i32x4*)AFB + (size_t)b * 3072;

    f32x4 acc[4][2];
    #pragma unroll
    for (int i = 0; i < 4; ++i)
        #pragma unroll
        for (int j = 0; j < 2; ++j) acc[i][j] = (f32x4){0.f, 0.f, 0.f, 0.f};

    int sm = (col & 1) ? (int)0x80008000 : 0;
    i32x4 SM = {sm, sm, sm, sm};

    auto tpart = [&](int ts) {
        i32x4 bh[2], bl[2];
        #pragma unroll
        for (int nj = 0; nj < 2; ++nj) {
            int tix = (((lt0 + nj) * 2 + ts) * 64 + lane) * 2;
            bh[nj] = tb[tix]; bl[nj] = tb[tix + 1];
        }
        #pragma unroll
        for (int mt = 0; mt < 4; ++mt) {
            int a0 = ((ts * 4 + mt) * 64 + lane) * 2;
            int a1 = (((2 + ts) * 4 + mt) * 64 + lane) * 2;
            i32x4 ah0 = ab[a0], al0 = ab[a0 + 1];
            i32x4 ah1 = ab[a1], al1 = ab[a1 + 1];
            bf16x8 AH0 = asbf(ah0), AL0 = asbf(al0), AH1 = asbf(ah1), AL1 = asbf(al1);
            #pragma unroll
            for (int nj = 0; nj < 2; ++nj) {
                bf16x8 BH = asbf(bh[nj]), BL = asbf(bl[nj]);
                acc[mt][nj] = MFMA(AH0, BH, acc[mt][nj]);
                acc[mt][nj] = MFMA(AL0, BH, acc[mt][nj]);
                acc[mt][nj] = MFMA(AH0, BL, acc[mt][nj]);
                bf16x8 BH2 = asbf(bh[nj] ^ SM), BL2 = asbf(bl[nj] ^ SM);
                acc[mt][nj] = MFMA(AH1, BH2, acc[mt][nj]);
                acc[mt][nj] = MFMA(AL1, BH2, acc[mt][nj]);
                acc[mt][nj] = MFMA(AH1, BL2, acc[mt][nj]);
            }
        }
    };
    auto xissue = [&](int ts, float xv[2][8]) {
        #pragma unroll
        for (int nj = 0; nj < 2; ++nj) {
            const float* xp = x + (size_t)(b * 64 + ts * 32 + kgrp * 8) * L_ + lbase + nj * 16 + col;
            #pragma unroll
            for (int e = 0; e < 8; ++e) xv[nj][e] = xp[(size_t)e * L_];
        }
    };
    auto xpart = [&](int ts, float xv[2][8]) {
        #pragma unroll
        for (int nj = 0; nj < 2; ++nj) {
            int h0 = pkbf(xv[nj][0], xv[nj][1]), h1 = pkbf(xv[nj][2], xv[nj][3]);
            int h2 = pkbf(xv[nj][4], xv[nj][5]), h3 = pkbf(xv[nj][6], xv[nj][7]);
            float r0 = xv[nj][0] - lo16f(h0), r1 = xv[nj][1] - hi16f(h0);
            float r2 = xv[nj][2] - lo16f(h1), r3 = xv[nj][3] - hi16f(h1);
            float r4 = xv[nj][4] - lo16f(h2), r5 = xv[nj][5] - hi16f(h2);
            float r6 = xv[nj][6] - lo16f(h3), r7 = xv[nj][7] - hi16f(h3);
            i32x4 xh = {h0, h1, h2, h3};
            i32x4 xl = {pkbf(r0, r1), pkbf(r2, r3), pkbf(r4, r5), pkbf(r6, r7)};
            bf16x8 XH = asbf(xh), XL = asbf(xl);
            #pragma unroll
            for (int mt = 0; mt < 4; ++mt) {
                int a = (((4 + ts) * 4 + mt) * 64 + lane) * 2;
                i32x4 ah = ab[a], al = ab[a + 1];
                bf16x8 AH = asbf(ah), AL = asbf(al);
                acc[mt][nj] = MFMA(AH, XH, acc[mt][nj]);
                acc[mt][nj] = MFMA(AL, XH, acc[mt][nj]);
                acc[mt][nj] = MFMA(AH, XL, acc[mt][nj]);
            }
        }
    };

    float xva[2][8], xvb[2][8];
    xissue(0, xva);          // x-loads ts=0 in flight
    tpart(0);                // 48 MFMAs overlap
    xissue(1, xvb);          // x-loads ts=1 in flight
    xpart(0, xva);           // consume ts=0
    tpart(1);                // 48 MFMAs overlap ts=1 loads
    xpart(1, xvb);

    #pragma unroll
    for (int mt = 0; mt < 4; ++mt) {
        #pragma unroll
        for (int r = 0; r < 4; ++r) {
            int c = mt * 16 + kgrp * 4 + r;
            float bias = bias2[b * 64 + c];
            float* op = out + (size_t)(b * 64 + c) * L_ + lbase + col;
            #pragma unroll
            for (int nj = 0; nj < 2; ++nj) {
                float v = acc[mt][nj][r] + bias;
                op[nj * 16] = v / (1.f + __expf(-v));
            }
        }
    }
}

extern "C" void kernel_launch(void* const* d_in, const int* in_sizes, int n_in,
                              void* d_out, int out_size, void* d_ws, size_t ws_size,
                              hipStream_t stream) {
    const float* x    = (const float*)d_in[0];
    const float* emb  = (const float*)d_in[1];
    const float* wpos = (const float*)d_in[2];
    const float* wneg = (const float*)d_in[3];
    const float* Arp  = (const float*)d_in[4];
    const float* Aip  = (const float*)d_in[5];
    const float* Arn  = (const float*)d_in[6];
    const float* Ain  = (const float*)d_in[7];
    const float* w1   = (const float*)d_in[8];
    const float* b1   = (const float*)d_in[9];
    const float* w2   = (const float*)d_in[10];
    const float* b2   = (const float*)d_in[11];
    const float* lw   = (const float*)d_in[12];
    const float* lb   = (const float*)d_in[13];
    float* out = (float*)d_out;
    float* ws = (float*)d_ws;
    ushort* TFB  = (ushort*)(ws + OFF_TFB);
    ushort* TLB  = (ushort*)(ws + OFF_TLB);
    ushort* AFB  = (ushort*)(ws + OFF_AFB);
    float*  XFRP = ws + OFF_XFRP;
    float*  AF   = ws + OFF_AF;
    float*  B2   = ws + OFF_B2;
    float*  PHI  = ws + OFF_PHI;
    float*  GB   = ws + OFF_GB;

    hipLaunchKernelGGL(k_trig2, dim3(8192), dim3(256), 0, stream, TLB, TFB);
    hipLaunchKernelGGL(k_phi,   dim3(16),   dim3(256), 0, stream, emb, Arp, Aip, Arn, Ain, PHI);
    hipLaunchKernelGGL(k_mlp,   dim3(32),   dim3(128), 0, stream, emb, w1, b1, w2, b2, GB);
    hipLaunchKernelGGL(k_dft,   dim3(512),  dim3(256), 0, stream, x, TLB, XFRP);
    hipLaunchKernelGGL(k_mix,   dim3(128),  dim3(256), 0, stream, XFRP, wpos, wneg, PHI, AF);
    hipLaunchKernelGGL(k_folda, dim3(32),   dim3(256), 0, stream, lw, lb, GB, AF, AFB, B2);
    hipLaunchKernelGGL(k_fuse,  dim3(2048), dim3(256), 0, stream, x, TFB, AFB, B2, out);
}

// Round 11
// 82.537 us; speedup vs baseline: 4.6769x; 1.2465x over previous
//
#include <hip/hip_runtime.h>
#include <math.h>

#define L_ 8192
#define EMB_ 256
#define HID_ 64

typedef __attribute__((ext_vector_type(8))) short bf16x8;
typedef __attribute__((ext_vector_type(4))) float f32x4;
typedef __attribute__((ext_vector_type(4))) int i32x4;

// workspace layout (floats)
#define OFF_TFB  0           // ushort[512][2][64][8]  synthesis B-frags, hi only
#define OFF_TLB  262144      // ushort[256][4][64][8]  analysis B-frags, hi only
#define OFF_AFB  524288      // ushort[32][6][4][64][16] A-frags (hi+lo)
#define OFF_XFRP 917504      // float[8][128][2048] per-Kseg DFT partials, transposed
#define OFF_AF   3014656     // float[32][128][64]  mix output rows
#define OFF_B2   3276800     // float[32*64]
#define OFF_PHI  3278848     // float[32*32*4]
#define OFF_GB   3282944     // float2[32*64]

__device__ inline int pkbf(float a, float b) {
    int r;
    asm volatile("v_cvt_pk_bf16_f32 %0, %1, %2" : "=v"(r) : "v"(a), "v"(b));
    return r;
}
__device__ inline bf16x8 asbf(i32x4 v) { union { i32x4 i; bf16x8 h; } u; u.i = v; return u.h; }
#define MFMA(A,B,C) __builtin_amdgcn_mfma_f32_16x16x32_bf16((A),(B),(C),0,0,0)

__device__ inline ushort f2bf(float v) {
    unsigned b = __float_as_uint(v);
    return (ushort)((b + 0x7FFFu + ((b >> 16) & 1u)) >> 16);
}
__device__ inline float bf2f(ushort h) { return __uint_as_float(((unsigned)h) << 16); }
__device__ inline float lo16f(int h) { return __uint_as_float(((unsigned)h) << 16); }
__device__ inline float hi16f(int h) { return __uint_as_float(((unsigned)h) & 0xFFFF0000u); }

// merged: trig tables (blocks 0..4095) + phi (4096..4111) + mlp (4112..4143)
__global__ __launch_bounds__(256) void k_init(ushort* __restrict__ TLB, ushort* __restrict__ TFB,
        const float* __restrict__ emb,
        const float* __restrict__ Arp, const float* __restrict__ Aip,
        const float* __restrict__ Arn, const float* __restrict__ Ain, float* __restrict__ phi,
        const float* __restrict__ w1, const float* __restrict__ b1,
        const float* __restrict__ w2, const float* __restrict__ b2, float* __restrict__ gb) {
    int bid = blockIdx.x;
    if (bid < 4096) {
        int idx = bid * 256 + threadIdx.x;   // 0..1048575
        int f, l; ushort* dst;
        if (idx < 524288) {                  // TLB: [kstep 256][ct 4][lane 64][e 8]
            int u = idx;
            int e = u & 7, lane = (u >> 3) & 63, ct = (u >> 9) & 3, kstep = u >> 11;
            l = kstep * 32 + ((lane >> 4) << 3) + e;
            f = ct * 16 + (lane & 15);
            dst = TLB + u;
        } else {                             // TFB: [lt 512][ts 2][lane 64][e 8]
            int u = idx - 524288;
            int e = u & 7, lane = (u >> 3) & 63, ts = (u >> 9) & 1, lt = u >> 10;
            l = lt * 16 + (lane & 15);
            f = ts * 32 + ((lane >> 4) << 3) + e;
            dst = TFB + u;
        }
        int fr = f & 31; bool sinp = (f & 32) != 0;
        int r = (fr * l) & (L_ - 1);
        float ang = (float)r * (6.283185307179586f / (float)L_);
        float v = sinp ? sinf(ang) : cosf(ang);
        *dst = f2bf(v);
    } else if (bid < 4112) {
        int tid = (bid - 4096) * 256 + threadIdx.x;   // (b*32+mm)*4+cmp
        int b = tid >> 7;
        int mm = (tid >> 2) & 31;
        int cmp = tid & 3;
        const float* A = (cmp == 0) ? Arp : (cmp == 1) ? Aip : (cmp == 2) ? Arn : Ain;
        const float4* e4 = (const float4*)(emb + b * EMB_);
        const float4* a4 = (const float4*)(A + mm * EMB_);
        float acc = 0.f;
        for (int q = 0; q < EMB_ / 4; ++q) {
            float4 ev = e4[q], av = a4[q];
            acc += ev.x * av.x + ev.y * av.y + ev.z * av.z + ev.w * av.w;
        }
        phi[tid] = acc;
    } else {
        __shared__ float h[HID_];
        int b = bid - 4112, t = threadIdx.x;
        if (t < HID_) {
            const float4* e4 = (const float4*)(emb + b * EMB_);
            const float4* w4 = (const float4*)(w1 + t * EMB_);
            float acc = b1[t];
            for (int q = 0; q < EMB_ / 4; ++q) {
                float4 ev = e4[q], wv = w4[q];
                acc += ev.x * wv.x + ev.y * wv.y + ev.z * wv.z + ev.w * wv.w;
            }
            h[t] = acc / (1.f + expf(-acc));
        }
        __syncthreads();
        if (t < 128) {
            float g = b2[t];
            const float4* h4 = (const float4*)h;
            const float4* w4 = (const float4*)(w2 + t * HID_);
            for (int q = 0; q < HID_ / 4; ++q) {
                float4 hv = h4[q], wv = w4[q];
                g += hv.x * wv.x + hv.y * wv.y + hv.z * wv.z + hv.w * wv.w;
            }
            if (t < 64) gb[(b * 64 + t) * 2 + 0] = 1.f + g;
            else        gb[(b * 64 + (t - 64)) * 2 + 1] = g;
        }
    }
}

// single-bf16 MFMA DFT; grid 1024 = stripe(128: 16 rows) x lseg(8: K=1024); 4 waves split K (256 each)
// stores transposed partials xfrp[lseg][col][row]
__global__ __launch_bounds__(256) void k_dft(const float* __restrict__ x,
        const ushort* __restrict__ TLB, float* __restrict__ xfrp) {
    __shared__ float sP[4][16][132];
    int stripe = blockIdx.x >> 3;
    int lseg = blockIdx.x & 7;
    int w = threadIdx.x >> 6;
    int lane = threadIdx.x & 63;
    int row = lane & 15, koff = (lane >> 4) << 3;
    int r0 = stripe * 16;
    int kb0 = lseg * 1024 + w * 256;

    f32x4 acc[8];
    #pragma unroll
    for (int i = 0; i < 8; ++i) acc[i] = (f32x4){0.f, 0.f, 0.f, 0.f};

    const float* ap = x + (size_t)(r0 + row) * L_ + kb0 + koff;
    const i32x4* tb = (const i32x4*)TLB;
    int tbase = (kb0 >> 5) * 256 + lane;    // i32x4 index; +256 per kstep, +64 per ct
    const i32x4 SM = {(int)0x80000000, (int)0x80000000, (int)0x80000000, (int)0x80000000};

    float4 xa0 = *(const float4*)(ap);
    float4 xc0 = *(const float4*)(ap + 4);
    float4 xa1 = *(const float4*)(ap + 32);
    float4 xc1 = *(const float4*)(ap + 36);
    for (int ks = 0; ks < 8; ++ks) {
        float4 nxa = {0,0,0,0}, nxc = {0,0,0,0};
        if (ks < 6) {
            nxa = *(const float4*)(ap + (ks + 2) * 32);
            nxc = *(const float4*)(ap + (ks + 2) * 32 + 4);
        }
        int h0 = pkbf(xa0.x, xa0.y), h1 = pkbf(xa0.z, xa0.w);
        int h2 = pkbf(xc0.x, xc0.y), h3 = pkbf(xc0.z, xc0.w);
        bf16x8 AH = asbf((i32x4){h0, h1, h2, h3});
        int tix = tbase + ks * 256;
        #pragma unroll
        for (int ct = 0; ct < 4; ++ct) {
            i32x4 bh = tb[tix + ct * 64];
            acc[ct] = MFMA(AH, asbf(bh), acc[ct]);
            acc[ct + 4] = MFMA(AH, asbf(bh ^ SM), acc[ct + 4]);
        }
        xa0 = xa1; xc0 = xc1; xa1 = nxa; xc1 = nxc;
    }
    int crow = (lane >> 4) << 2;
    int ccol = lane & 15;
    #pragma unroll
    for (int ct = 0; ct < 8; ++ct)
        #pragma unroll
        for (int r = 0; r < 4; ++r)
            sP[w][crow + r][ct * 16 + ccol] = acc[ct][r];
    __syncthreads();
    #pragma unroll
    for (int i = 0; i < 8; ++i) {
        int e = threadIdx.x + 256 * i;     // 0..2047
        int rr = e & 15, cc = e >> 4;
        float s = sP[0][rr][cc] + sP[1][rr][cc] + sP[2][rr][cc] + sP[3][rr][cc];
        xfrp[((size_t)(lseg * 128 + cc)) * 2048 + r0 + rr] = s;
    }
}

// mode mixing -> AF rows 0..127. grid 128 = [mm 32][side 2][bh 2]; 256 thr = bg(4) x o(64)
__global__ __launch_bounds__(256) void k_mix(const float* __restrict__ xfrt,
        const float* __restrict__ wpos, const float* __restrict__ wneg,
        const float* __restrict__ phi, float* __restrict__ afull) {
    __shared__ float sW[64][64][2];     // [i][o][re/im]
    __shared__ float sXr[16][64], sXi[16][64];   // [b_local][i]
    int bi = blockIdx.x;
    int bh = bi & 1, side = (bi >> 1) & 1, mm = bi >> 2;
    int tid = threadIdx.x;
    int slot = side ? (31 - mm) : mm;
    int colR = side ? (64 + slot) : mm;
    int colI = side ? (96 + slot) : (32 + mm);

    const float* W = side ? wneg : wpos;
    #pragma unroll
    for (int j = 0; j < 16; ++j) {
        int fidx = tid + 256 * j;       // 0..4095 = i*64+o
        int i = fidx >> 6, o = fidx & 63;
        float2 wv = *(const float2*)&W[(size_t)(i * 64 + o) * 64 + mm * 2];
        sW[i][o][0] = wv.x;
        sW[i][o][1] = wv.y;
    }
    {
        const float4* pR = (const float4*)(xfrt + (size_t)colR * 2048 + bh * 1024);
        const float4* pI = (const float4*)(xfrt + (size_t)colI * 2048 + bh * 1024);
        float4 aR = {0, 0, 0, 0}, aI = {0, 0, 0, 0};
        #pragma unroll
        for (int s = 0; s < 8; ++s) {
            float4 vR = pR[(size_t)s * 65536 + tid];
            float4 vI = pI[(size_t)s * 65536 + tid];
            aR.x += vR.x; aR.y += vR.y; aR.z += vR.z; aR.w += vR.w;
            aI.x += vI.x; aI.y += vI.y; aI.z += vI.z; aI.w += vI.w;
        }
        if (!side) { aI.x = -aI.x; aI.y = -aI.y; aI.z = -aI.z; aI.w = -aI.w; }
        *(float4*)&sXr[tid >> 4][(tid & 15) * 4] = aR;
        *(float4*)&sXi[tid >> 4][(tid & 15) * 4] = aI;
    }
    __syncthreads();

    int o = tid & 63, bg = tid >> 6;
    const float invL = 1.f / (float)L_;
    float fac = (slot == 0) ? invL : 2.f * invL;
    int comp = side ? 2 : 0;
    #pragma unroll
    for (int bl = 0; bl < 4; ++bl) {
        int b_local = bg * 4 + bl;
        int b = bh * 16 + b_local;
        float sre = 0.f, sim = 0.f;
        #pragma unroll 16
        for (int i = 0; i < 64; ++i) {
            float wr = sW[i][o][0], wi = sW[i][o][1];
            float xr = sXr[b_local][i], xi = sXi[b_local][i];
            sre += xr * wr - xi * wi;
            sim += xr * wi + xi * wr;
        }
        const float* ph = &phi[(b * 32 + mm) * 4 + (side ? 2 : 0)];
        float phr = ph[0], phim = ph[1];
        float Pre = sre * phr - sim * phim;
        float Pim = sre * phim + sim * phr;
        float a = fac * Pre;
        float bcoef = (slot == 0) ? 0.f : (side ? 2.f * invL * Pim : -2.f * invL * Pim);
        afull[((size_t)b * 128 + comp * 32 + slot) * 64 + o] = a;
        afull[((size_t)b * 128 + (comp + 1) * 32 + slot) * 64 + o] = bcoef;
    }
}

// fold coefficients into MFMA A-frag table: ks 0..1 = A0, 2..3 = A1, 4..5 = Ax
__global__ __launch_bounds__(256) void k_folda(const float* __restrict__ lw,
        const float* __restrict__ lb, const float* __restrict__ gb,
        const float* __restrict__ af, ushort* __restrict__ afb, float* __restrict__ bias2) {
    int b = blockIdx.x, tid = threadIdx.x;
    const float* afs = af + (size_t)b * 128 * 64;
    ushort* dst = afb + (size_t)b * 24576;
    #pragma unroll
    for (int j = 0; j < 48; ++j) {
        int u = tid + 256 * j;   // 0..12287 : [ks 6][mt 4][lane 64][e 8]
        int e = u & 7, lane = (u >> 3) & 63, mt = (u >> 9) & 3, ks = u >> 11;
        int c = mt * 16 + (lane & 15);
        int kk = ((lane >> 4) << 3) + e;
        float v = (ks < 4) ? afs[(ks * 32 + kk) * 64 + c]
                           : lw[c * 64 + (ks - 4) * 32 + kk] * gb[(b * 64 + c) * 2];
        ushort hi = f2bf(v);
        ushort lo = f2bf(v - bf2f(hi));
        int base = ((ks * 4 + mt) * 64 + lane) * 16;
        dst[base + e] = hi;
        dst[base + 8 + e] = lo;
    }
    if (tid < 64) {
        float g1 = gb[(b * 64 + tid) * 2], be = gb[(b * 64 + tid) * 2 + 1];
        bias2[b * 64 + tid] = lb[tid] * g1 + be;
    }
}

// MFMA epilogue GEMM: out[b][c][l] = silu( sum_k A[k][c] * B[k][l] + bias2[c] ),
// B = [T(64); (-1)^l T(64); x[b](64)]. grid 2048 = b(32) x lt(64); wave: 64c x 32l.
// T-part bf16-hi only (spectral path ~1e-4 of output); x-part keeps split precision.
__global__ __launch_bounds__(256, 3) void k_fuse(const float* __restrict__ x,
        const ushort* __restrict__ TFB, const ushort* __restrict__ AFB,
        const float* __restrict__ bias2, float* __restrict__ out) {
    int b = blockIdx.x >> 6, lt = blockIdx.x & 63;
    int w = threadIdx.x >> 6, lane = threadIdx.x & 63;
    int col = lane & 15, kgrp = lane >> 4;
    int lbase = lt * 128 + w * 32;
    int lt0 = lbase >> 4;
    const i32x4* tb = (const i32x4*)TFB;
    const i32x4* ab = (const i32x4*)AFB + (size_t)b * 3072;

    f32x4 acc[4][2];
    #pragma unroll
    for (int i = 0; i < 4; ++i)
        #pragma unroll
        for (int j = 0; j < 2; ++j) acc[i][j] = (f32x4){0.f, 0.f, 0.f, 0.f};

    int sm = (col & 1) ? (int)0x80008000 : 0;
    i32x4 SM = {sm, sm, sm, sm};

    auto tpart = [&](int ts) {
        i32x4 bh[2];
        #pragma unroll
        for (int nj = 0; nj < 2; ++nj)
            bh[nj] = tb[((lt0 + nj) * 2 + ts) * 64 + lane];
        #pragma unroll
        for (int mt = 0; mt < 4; ++mt) {
            i32x4 ah0 = ab[((ts * 4 + mt) * 64 + lane) * 2];
            i32x4 ah1 = ab[(((2 + ts) * 4 + mt) * 64 + lane) * 2];
            bf16x8 AH0 = asbf(ah0), AH1 = asbf(ah1);
            #pragma unroll
            for (int nj = 0; nj < 2; ++nj) {
                acc[mt][nj] = MFMA(AH0, asbf(bh[nj]), acc[mt][nj]);
                acc[mt][nj] = MFMA(AH1, asbf(bh[nj] ^ SM), acc[mt][nj]);
            }
        }
    };
    auto xissue = [&](int ts, float xv[2][8]) {
        #pragma unroll
        for (int nj = 0; nj < 2; ++nj) {
            const float* xp = x + (size_t)(b * 64 + ts * 32 + kgrp * 8) * L_ + lbase + nj * 16 + col;
            #pragma unroll
            for (int e = 0; e < 8; ++e) xv[nj][e] = xp[(size_t)e * L_];
        }
    };
    auto xpart = [&](int ts, float xv[2][8]) {
        #pragma unroll
        for (int nj = 0; nj < 2; ++nj) {
            int h0 = pkbf(xv[nj][0], xv[nj][1]), h1 = pkbf(xv[nj][2], xv[nj][3]);
            int h2 = pkbf(xv[nj][4], xv[nj][5]), h3 = pkbf(xv[nj][6], xv[nj][7]);
            float r0 = xv[nj][0] - lo16f(h0), r1 = xv[nj][1] - hi16f(h0);
            float r2 = xv[nj][2] - lo16f(h1), r3 = xv[nj][3] - hi16f(h1);
            float r4 = xv[nj][4] - lo16f(h2), r5 = xv[nj][5] - hi16f(h2);
            float r6 = xv[nj][6] - lo16f(h3), r7 = xv[nj][7] - hi16f(h3);
            i32x4 xh = {h0, h1, h2, h3};
            i32x4 xl = {pkbf(r0, r1), pkbf(r2, r3), pkbf(r4, r5), pkbf(r6, r7)};
            bf16x8 XH = asbf(xh), XL = asbf(xl);
            #pragma unroll
            for (int mt = 0; mt < 4; ++mt) {
                int a = (((4 + ts) * 4 + mt) * 64 + lane) * 2;
                i32x4 ah = ab[a], al = ab[a + 1];
                bf16x8 AH = asbf(ah), AL = asbf(al);
                acc[mt][nj] = MFMA(AH, XH, acc[mt][nj]);
                acc[mt][nj] = MFMA(AL, XH, acc[mt][nj]);
                acc[mt][nj] = MFMA(AH, XL, acc[mt][nj]);
            }
        }
    };

    float xva[2][8], xvb[2][8];
    xissue(0, xva);          // x-loads ts=0 in flight
    tpart(0);                // MFMAs overlap
    xissue(1, xvb);          // x-loads ts=1 in flight
    xpart(0, xva);           // consume ts=0
    tpart(1);                // MFMAs overlap ts=1 loads
    xpart(1, xvb);

    #pragma unroll
    for (int mt = 0; mt < 4; ++mt) {
        #pragma unroll
        for (int r = 0; r < 4; ++r) {
            int c = mt * 16 + kgrp * 4 + r;
            float bias = bias2[b * 64 + c];
            float* op = out + (size_t)(b * 64 + c) * L_ + lbase + col;
            #pragma unroll
            for (int nj = 0; nj < 2; ++nj) {
                float v = acc[mt][nj][r] + bias;
                op[nj * 16] = v / (1.f + __expf(-v));
            }
        }
    }
}

extern "C" void kernel_launch(void* const* d_in, const int* in_sizes, int n_in,
                              void* d_out, int out_size, void* d_ws, size_t ws_size,
                              hipStream_t stream) {
    const float* x    = (const float*)d_in[0];
    const float* emb  = (const float*)d_in[1];
    const float* wpos = (const float*)d_in[2];
    const float* wneg = (const float*)d_in[3];
    const float* Arp  = (const float*)d_in[4];
    const float* Aip  = (const float*)d_in[5];
    const float* Arn  = (const float*)d_in[6];
    const float* Ain  = (const float*)d_in[7];
    const float* w1   = (const float*)d_in[8];
    const float* b1   = (const float*)d_in[9];
    const float* w2   = (const float*)d_in[10];
    const float* b2   = (const float*)d_in[11];
    const float* lw   = (const float*)d_in[12];
    const float* lb   = (const float*)d_in[13];
    float* out = (float*)d_out;
    float* ws = (float*)d_ws;
    ushort* TFB  = (ushort*)(ws + OFF_TFB);
    ushort* TLB  = (ushort*)(ws + OFF_TLB);
    ushort* AFB  = (ushort*)(ws + OFF_AFB);
    float*  XFRP = ws + OFF_XFRP;
    float*  AF   = ws + OFF_AF;
    float*  B2   = ws + OFF_B2;
    float*  PHI  = ws + OFF_PHI;
    float*  GB   = ws + OFF_GB;

    hipLaunchKernelGGL(k_init,  dim3(4144), dim3(256), 0, stream,
                       TLB, TFB, emb, Arp, Aip, Arn, Ain, PHI, w1, b1, w2, b2, GB);
    hipLaunchKernelGGL(k_dft,   dim3(1024), dim3(256), 0, stream, x, TLB, XFRP);
    hipLaunchKernelGGL(k_mix,   dim3(128),  dim3(256), 0, stream, XFRP, wpos, wneg, PHI, AF);
    hipLaunchKernelGGL(k_folda, dim3(32),   dim3(256), 0, stream, lw, lb, GB, AF, AFB, B2);
    hipLaunchKernelGGL(k_fuse,  dim3(2048), dim3(256), 0, stream, x, TFB, AFB, B2, out);
}

// Round 12
// 72.492 us; speedup vs baseline: 5.3250x; 1.1386x over previous
//
#include <hip/hip_runtime.h>
#include <math.h>

#define L_ 8192
#define EMB_ 256
#define HID_ 64

typedef __attribute__((ext_vector_type(8))) short bf16x8;
typedef __attribute__((ext_vector_type(4))) float f32x4;
typedef __attribute__((ext_vector_type(4))) int i32x4;

// workspace layout (floats)
#define OFF_TFB  0           // ushort[512][2][64][8]  synthesis B-frags, hi only
#define OFF_TLB  262144      // ushort[256][4][64][8]  analysis B-frags, hi only
#define OFF_AFB  524288      // ushort[32][6][4][64][16] A-frags (hi+lo)
#define OFF_XFRP 917504      // float[8][128][2048] per-Kseg DFT partials, transposed
#define OFF_B2   3014656     // float[32*64]
#define OFF_PHI  3016704     // float[32*32*4]
#define OFF_GB   3020800     // float2[32*64]

__device__ inline int pkbf(float a, float b) {
    int r;
    asm volatile("v_cvt_pk_bf16_f32 %0, %1, %2" : "=v"(r) : "v"(a), "v"(b));
    return r;
}
__device__ inline bf16x8 asbf(i32x4 v) { union { i32x4 i; bf16x8 h; } u; u.i = v; return u.h; }
#define MFMA(A,B,C) __builtin_amdgcn_mfma_f32_16x16x32_bf16((A),(B),(C),0,0,0)

__device__ inline ushort f2bf(float v) {
    unsigned b = __float_as_uint(v);
    return (ushort)((b + 0x7FFFu + ((b >> 16) & 1u)) >> 16);
}
__device__ inline float bf2f(ushort h) { return __uint_as_float(((unsigned)h) << 16); }

// merged: trig tables (blocks 0..4095) + phi (4096..4111) + mlp (4112..4143)
__global__ __launch_bounds__(256) void k_init(ushort* __restrict__ TLB, ushort* __restrict__ TFB,
        const float* __restrict__ emb,
        const float* __restrict__ Arp, const float* __restrict__ Aip,
        const float* __restrict__ Arn, const float* __restrict__ Ain, float* __restrict__ phi,
        const float* __restrict__ w1, const float* __restrict__ b1,
        const float* __restrict__ w2, const float* __restrict__ b2, float* __restrict__ gb) {
    int bid = blockIdx.x;
    if (bid < 4096) {
        int idx = bid * 256 + threadIdx.x;   // 0..1048575
        int f, l; ushort* dst;
        if (idx < 524288) {                  // TLB: [kstep 256][ct 4][lane 64][e 8]
            int u = idx;
            int e = u & 7, lane = (u >> 3) & 63, ct = (u >> 9) & 3, kstep = u >> 11;
            l = kstep * 32 + ((lane >> 4) << 3) + e;
            f = ct * 16 + (lane & 15);
            dst = TLB + u;
        } else {                             // TFB: [lt 512][ts 2][lane 64][e 8]
            int u = idx - 524288;
            int e = u & 7, lane = (u >> 3) & 63, ts = (u >> 9) & 1, lt = u >> 10;
            l = lt * 16 + (lane & 15);
            f = ts * 32 + ((lane >> 4) << 3) + e;
            dst = TFB + u;
        }
        int fr = f & 31; bool sinp = (f & 32) != 0;
        int r = (fr * l) & (L_ - 1);
        float ang = (float)r * (6.283185307179586f / (float)L_);
        float v = sinp ? sinf(ang) : cosf(ang);
        *dst = f2bf(v);
    } else if (bid < 4112) {
        int tid = (bid - 4096) * 256 + threadIdx.x;   // (b*32+mm)*4+cmp
        int b = tid >> 7;
        int mm = (tid >> 2) & 31;
        int cmp = tid & 3;
        const float* A = (cmp == 0) ? Arp : (cmp == 1) ? Aip : (cmp == 2) ? Arn : Ain;
        const float4* e4 = (const float4*)(emb + b * EMB_);
        const float4* a4 = (const float4*)(A + mm * EMB_);
        float acc = 0.f;
        for (int q = 0; q < EMB_ / 4; ++q) {
            float4 ev = e4[q], av = a4[q];
            acc += ev.x * av.x + ev.y * av.y + ev.z * av.z + ev.w * av.w;
        }
        phi[tid] = acc;
    } else {
        __shared__ float h[HID_];
        int b = bid - 4112, t = threadIdx.x;
        if (t < HID_) {
            const float4* e4 = (const float4*)(emb + b * EMB_);
            const float4* w4 = (const float4*)(w1 + t * EMB_);
            float acc = b1[t];
            for (int q = 0; q < EMB_ / 4; ++q) {
                float4 ev = e4[q], wv = w4[q];
                acc += ev.x * wv.x + ev.y * wv.y + ev.z * wv.z + ev.w * wv.w;
            }
            h[t] = acc / (1.f + expf(-acc));
        }
        __syncthreads();
        if (t < 128) {
            float g = b2[t];
            const float4* h4 = (const float4*)h;
            const float4* w4 = (const float4*)(w2 + t * HID_);
            for (int q = 0; q < HID_ / 4; ++q) {
                float4 hv = h4[q], wv = w4[q];
                g += hv.x * wv.x + hv.y * wv.y + hv.z * wv.z + hv.w * wv.w;
            }
            if (t < 64) gb[(b * 64 + t) * 2 + 0] = 1.f + g;
            else        gb[(b * 64 + (t - 64)) * 2 + 1] = g;
        }
    }
}

// single-bf16 MFMA DFT; grid 1024 = stripe(128: 16 rows) x lseg(8: K=1024); 4 waves split K
// depth-3 x prefetch + 1-deep TLB prefetch; stores transposed partials xfrp[lseg][col][row]
__global__ __launch_bounds__(256) void k_dft(const float* __restrict__ x,
        const ushort* __restrict__ TLB, float* __restrict__ xfrp) {
    __shared__ float sP[4][16][132];
    int stripe = blockIdx.x >> 3;
    int lseg = blockIdx.x & 7;
    int w = threadIdx.x >> 6;
    int lane = threadIdx.x & 63;
    int row = lane & 15, koff = (lane >> 4) << 3;
    int r0 = stripe * 16;
    int kb0 = lseg * 1024 + w * 256;

    f32x4 acc[8];
    #pragma unroll
    for (int i = 0; i < 8; ++i) acc[i] = (f32x4){0.f, 0.f, 0.f, 0.f};

    const float* ap = x + (size_t)(r0 + row) * L_ + kb0 + koff;
    const i32x4* tb = (const i32x4*)TLB;
    int tbase = (kb0 >> 5) * 256 + lane;    // i32x4 index; +256 per kstep, +64 per ct
    const i32x4 SM = {(int)0x80000000, (int)0x80000000, (int)0x80000000, (int)0x80000000};

    float4 xa0 = *(const float4*)(ap);
    float4 xc0 = *(const float4*)(ap + 4);
    float4 xa1 = *(const float4*)(ap + 32);
    float4 xc1 = *(const float4*)(ap + 36);
    float4 xa2 = *(const float4*)(ap + 64);
    float4 xc2 = *(const float4*)(ap + 68);
    i32x4 t0 = tb[tbase], t1 = tb[tbase + 64], t2 = tb[tbase + 128], t3 = tb[tbase + 192];
    for (int ks = 0; ks < 8; ++ks) {
        float4 nxa = {0,0,0,0}, nxc = {0,0,0,0};
        i32x4 n0 = t0, n1 = t1, n2 = t2, n3 = t3;
        if (ks < 5) {
            nxa = *(const float4*)(ap + (ks + 3) * 32);
            nxc = *(const float4*)(ap + (ks + 3) * 32 + 4);
        }
        if (ks < 7) {
            int ti = tbase + (ks + 1) * 256;
            n0 = tb[ti]; n1 = tb[ti + 64]; n2 = tb[ti + 128]; n3 = tb[ti + 192];
        }
        int h0 = pkbf(xa0.x, xa0.y), h1 = pkbf(xa0.z, xa0.w);
        int h2 = pkbf(xc0.x, xc0.y), h3 = pkbf(xc0.z, xc0.w);
        bf16x8 AH = asbf((i32x4){h0, h1, h2, h3});
        acc[0] = MFMA(AH, asbf(t0), acc[0]); acc[4] = MFMA(AH, asbf(t0 ^ SM), acc[4]);
        acc[1] = MFMA(AH, asbf(t1), acc[1]); acc[5] = MFMA(AH, asbf(t1 ^ SM), acc[5]);
        acc[2] = MFMA(AH, asbf(t2), acc[2]); acc[6] = MFMA(AH, asbf(t2 ^ SM), acc[6]);
        acc[3] = MFMA(AH, asbf(t3), acc[3]); acc[7] = MFMA(AH, asbf(t3 ^ SM), acc[7]);
        xa0 = xa1; xc0 = xc1; xa1 = xa2; xc1 = xc2; xa2 = nxa; xc2 = nxc;
        t0 = n0; t1 = n1; t2 = n2; t3 = n3;
    }
    int crow = (lane >> 4) << 2;
    int ccol = lane & 15;
    #pragma unroll
    for (int ct = 0; ct < 8; ++ct)
        #pragma unroll
        for (int r = 0; r < 4; ++r)
            sP[w][crow + r][ct * 16 + ccol] = acc[ct][r];
    __syncthreads();
    #pragma unroll
    for (int i = 0; i < 8; ++i) {
        int e = threadIdx.x + 256 * i;     // 0..2047
        int rr = e & 15, cc = e >> 4;
        float s = sP[0][rr][cc] + sP[1][rr][cc] + sP[2][rr][cc] + sP[3][rr][cc];
        xfrp[((size_t)(lseg * 128 + cc)) * 2048 + r0 + rr] = s;
    }
}

// mode mixing -> AFB fragments directly.
// blocks 0..127: [mm 32][side 2][bh 2] spectral rows; blocks 128..159: Ax fold + bias2 per b
__global__ __launch_bounds__(256) void k_mix(const float* __restrict__ xfrt,
        const float* __restrict__ wpos, const float* __restrict__ wneg,
        const float* __restrict__ phi, const float* __restrict__ lw,
        const float* __restrict__ lb, const float* __restrict__ gb,
        ushort* __restrict__ afb, float* __restrict__ bias2) {
    int bi = blockIdx.x;
    int tid = threadIdx.x;
    if (bi >= 128) {                 // Ax fold + bias2
        int b = bi - 128;
        ushort* dst = afb + (size_t)b * 24576;
        #pragma unroll
        for (int j = 0; j < 16; ++j) {
            int u = tid + 256 * j;   // 0..4095 : [ks2 2][mt 4][lane 64][e 8]
            int e = u & 7, lane = (u >> 3) & 63, mt = (u >> 9) & 3, ks2 = u >> 11;
            int c = mt * 16 + (lane & 15);
            int kk = ((lane >> 4) << 3) + e;
            float v = lw[c * 64 + ks2 * 32 + kk] * gb[(b * 64 + c) * 2];
            ushort hi = f2bf(v);
            int base = (((4 + ks2) * 4 + mt) * 64 + lane) * 16;
            dst[base + e] = hi;
            dst[base + 8 + e] = f2bf(v - bf2f(hi));
        }
        if (tid < 64) {
            float g1 = gb[(b * 64 + tid) * 2], be = gb[(b * 64 + tid) * 2 + 1];
            bias2[b * 64 + tid] = lb[tid] * g1 + be;
        }
        return;
    }
    __shared__ float sW[64][64][2];     // [i][o][re/im]
    __shared__ float sXr[16][64], sXi[16][64];   // [b_local][i]
    int bh = bi & 1, side = (bi >> 1) & 1, mm = bi >> 2;
    int slot = side ? (31 - mm) : mm;
    int colR = side ? (64 + slot) : mm;
    int colI = side ? (96 + slot) : (32 + mm);

    const float* W = side ? wneg : wpos;
    #pragma unroll
    for (int j = 0; j < 16; ++j) {
        int fidx = tid + 256 * j;       // 0..4095 = i*64+o
        int i = fidx >> 6, o = fidx & 63;
        float2 wv = *(const float2*)&W[(size_t)(i * 64 + o) * 64 + mm * 2];
        sW[i][o][0] = wv.x;
        sW[i][o][1] = wv.y;
    }
    {
        const float4* pR = (const float4*)(xfrt + (size_t)colR * 2048 + bh * 1024);
        const float4* pI = (const float4*)(xfrt + (size_t)colI * 2048 + bh * 1024);
        float4 aR = {0, 0, 0, 0}, aI = {0, 0, 0, 0};
        #pragma unroll
        for (int s = 0; s < 8; ++s) {
            float4 vR = pR[(size_t)s * 65536 + tid];
            float4 vI = pI[(size_t)s * 65536 + tid];
            aR.x += vR.x; aR.y += vR.y; aR.z += vR.z; aR.w += vR.w;
            aI.x += vI.x; aI.y += vI.y; aI.z += vI.z; aI.w += vI.w;
        }
        if (!side) { aI.x = -aI.x; aI.y = -aI.y; aI.z = -aI.z; aI.w = -aI.w; }
        *(float4*)&sXr[tid >> 4][(tid & 15) * 4] = aR;
        *(float4*)&sXi[tid >> 4][(tid & 15) * 4] = aI;
    }
    __syncthreads();

    int o = tid & 63, bg = tid >> 6;
    const float invL = 1.f / (float)L_;
    float fac = (slot == 0) ? invL : 2.f * invL;
    int comp = side ? 2 : 0;
    int e = slot & 7, kgrp = slot >> 3;
    int mt = o >> 4, lane = kgrp * 16 + (o & 15);
    #pragma unroll
    for (int bl = 0; bl < 4; ++bl) {
        int b_local = bg * 4 + bl;
        int b = bh * 16 + b_local;
        float sre = 0.f, sim = 0.f;
        #pragma unroll 16
        for (int i = 0; i < 64; ++i) {
            float wr = sW[i][o][0], wi = sW[i][o][1];
            float xr = sXr[b_local][i], xi = sXi[b_local][i];
            sre += xr * wr - xi * wi;
            sim += xr * wi + xi * wr;
        }
        const float* ph = &phi[(b * 32 + mm) * 4 + (side ? 2 : 0)];
        float phr = ph[0], phim = ph[1];
        float Pre = sre * phr - sim * phim;
        float Pim = sre * phim + sim * phr;
        float a = fac * Pre;
        float bcoef = (slot == 0) ? 0.f : (side ? 2.f * invL * Pim : -2.f * invL * Pim);
        ushort* dst = afb + (size_t)b * 24576;
        ushort hiA = f2bf(a);
        int baseA = ((comp * 4 + mt) * 64 + lane) * 16;
        dst[baseA + e] = hiA;
        dst[baseA + 8 + e] = f2bf(a - bf2f(hiA));
        ushort hiB = f2bf(bcoef);
        int baseB = (((comp + 1) * 4 + mt) * 64 + lane) * 16;
        dst[baseB + e] = hiB;
        dst[baseB + 8 + e] = f2bf(bcoef - bf2f(hiB));
    }
}

// MFMA epilogue GEMM: out[b][c][l] = silu( sum_k A[k][c] * B[k][l] + bias2[c] ),
// B = [T(64); (-1)^l T(64); x[b](64)]. grid 2048 = b(32) x lt(64); wave: 64c x 32l.
// All paths bf16-hi only (validated scale analysis); x-loads issued early (T14).
__global__ __launch_bounds__(256, 3) void k_fuse(const float* __restrict__ x,
        const ushort* __restrict__ TFB, const ushort* __restrict__ AFB,
        const float* __restrict__ bias2, float* __restrict__ out) {
    int b = blockIdx.x >> 6, lt = blockIdx.x & 63;
    int w = threadIdx.x >> 6, lane = threadIdx.x & 63;
    int col = lane & 15, kgrp = lane >> 4;
    int lbase = lt * 128 + w * 32;
    int lt0 = lbase >> 4;
    const i32x4* tb = (const i32x4*)TFB;
    const i32x4* ab = (const i32x4*)AFB + (size_t)b * 3072;

    f32x4 acc[4][2];
    #pragma unroll
    for (int i = 0; i < 4; ++i)
        #pragma unroll
        for (int j = 0; j < 2; ++j) acc[i][j] = (f32x4){0.f, 0.f, 0.f, 0.f};

    int sm = (col & 1) ? (int)0x80008000 : 0;
    i32x4 SM = {sm, sm, sm, sm};

    auto tpart = [&](int ts) {
        i32x4 bh[2];
        #pragma unroll
        for (int nj = 0; nj < 2; ++nj)
            bh[nj] = tb[((lt0 + nj) * 2 + ts) * 64 + lane];
        #pragma unroll
        for (int mt = 0; mt < 4; ++mt) {
            i32x4 ah0 = ab[((ts * 4 + mt) * 64 + lane) * 2];
            i32x4 ah1 = ab[(((2 + ts) * 4 + mt) * 64 + lane) * 2];
            bf16x8 AH0 = asbf(ah0), AH1 = asbf(ah1);
            #pragma unroll
            for (int nj = 0; nj < 2; ++nj) {
                acc[mt][nj] = MFMA(AH0, asbf(bh[nj]), acc[mt][nj]);
                acc[mt][nj] = MFMA(AH1, asbf(bh[nj] ^ SM), acc[mt][nj]);
            }
        }
    };
    auto xissue = [&](int ts, float xv[2][8]) {
        #pragma unroll
        for (int nj = 0; nj < 2; ++nj) {
            const float* xp = x + (size_t)(b * 64 + ts * 32 + kgrp * 8) * L_ + lbase + nj * 16 + col;
            #pragma unroll
            for (int e = 0; e < 8; ++e) xv[nj][e] = xp[(size_t)e * L_];
        }
    };
    auto xpart = [&](int ts, float xv[2][8]) {
        #pragma unroll
        for (int nj = 0; nj < 2; ++nj) {
            int h0 = pkbf(xv[nj][0], xv[nj][1]), h1 = pkbf(xv[nj][2], xv[nj][3]);
            int h2 = pkbf(xv[nj][4], xv[nj][5]), h3 = pkbf(xv[nj][6], xv[nj][7]);
            bf16x8 XH = asbf((i32x4){h0, h1, h2, h3});
            #pragma unroll
            for (int mt = 0; mt < 4; ++mt) {
                i32x4 ah = ab[(((4 + ts) * 4 + mt) * 64 + lane) * 2];
                acc[mt][nj] = MFMA(asbf(ah), XH, acc[mt][nj]);
            }
        }
    };

    float xva[2][8], xvb[2][8];
    xissue(0, xva);          // x-loads ts=0 in flight
    tpart(0);                // MFMAs overlap
    xissue(1, xvb);          // x-loads ts=1 in flight
    xpart(0, xva);           // consume ts=0
    tpart(1);                // MFMAs overlap ts=1 loads
    xpart(1, xvb);

    #pragma unroll
    for (int mt = 0; mt < 4; ++mt) {
        #pragma unroll
        for (int r = 0; r < 4; ++r) {
            int c = mt * 16 + kgrp * 4 + r;
            float bias = bias2[b * 64 + c];
            float* op = out + (size_t)(b * 64 + c) * L_ + lbase + col;
            #pragma unroll
            for (int nj = 0; nj < 2; ++nj) {
                float v = acc[mt][nj][r] + bias;
                op[nj * 16] = v / (1.f + __expf(-v));
            }
        }
    }
}

extern "C" void kernel_launch(void* const* d_in, const int* in_sizes, int n_in,
                              void* d_out, int out_size, void* d_ws, size_t ws_size,
                              hipStream_t stream) {
    const float* x    = (const float*)d_in[0];
    const float* emb  = (const float*)d_in[1];
    const float* wpos = (const float*)d_in[2];
    const float* wneg = (const float*)d_in[3];
    const float* Arp  = (const float*)d_in[4];
    const float* Aip  = (const float*)d_in[5];
    const float* Arn  = (const float*)d_in[6];
    const float* Ain  = (const float*)d_in[7];
    const float* w1   = (const float*)d_in[8];
    const float* b1   = (const float*)d_in[9];
    const float* w2   = (const float*)d_in[10];
    const float* b2   = (const float*)d_in[11];
    const float* lw   = (const float*)d_in[12];
    const float* lb   = (const float*)d_in[13];
    float* out = (float*)d_out;
    float* ws = (float*)d_ws;
    ushort* TFB  = (ushort*)(ws + OFF_TFB);
    ushort* TLB  = (ushort*)(ws + OFF_TLB);
    ushort* AFB  = (ushort*)(ws + OFF_AFB);
    float*  XFRP = ws + OFF_XFRP;
    float*  B2   = ws + OFF_B2;
    float*  PHI  = ws + OFF_PHI;
    float*  GB   = ws + OFF_GB;

    hipLaunchKernelGGL(k_init,  dim3(4144), dim3(256), 0, stream,
                       TLB, TFB, emb, Arp, Aip, Arn, Ain, PHI, w1, b1, w2, b2, GB);
    hipLaunchKernelGGL(k_dft,   dim3(1024), dim3(256), 0, stream, x, TLB, XFRP);
    hipLaunchKernelGGL(k_mix,   dim3(160),  dim3(256), 0, stream, XFRP, wpos, wneg, PHI,
                       lw, lb, GB, AFB, B2);
    hipLaunchKernelGGL(k_fuse,  dim3(2048), dim3(256), 0, stream, x, TFB, AFB, B2, out);
}